// Round 10
// baseline (159.310 us; speedup 1.0000x reference)
//
#include <hip/hip_runtime.h>
#include <hip/hip_bf16.h>
#include <math.h>

#define BATCH 4
#define SEQ   4096
#define DIM   256
#define AS1 __attribute__((address_space(1)))
#define AS3 __attribute__((address_space(3)))

typedef __attribute__((ext_vector_type(8))) short  bf16x8;
typedef __attribute__((ext_vector_type(4))) short  bf16x4;
typedef __attribute__((ext_vector_type(4))) float  f32x4;
typedef __attribute__((ext_vector_type(4))) int    i32x4;

#define LOG2E 1.44269504088896340736f

__device__ __forceinline__ short f2bf(float f) {
    union { float f; unsigned u; } v; v.f = f;
    unsigned r = (v.u + 0x7fffu + ((v.u >> 16) & 1u)) >> 16;
    return (short)r;
}

__device__ __forceinline__ void gload_lds16(const void* g, void* l) {
    __builtin_amdgcn_global_load_lds((const AS1 void*)g, (AS3 void*)l, 16, 0, 0);
}

// ---------------------------------------------------------------------------
// Projection (single): out[n][e] = (sum_d A[n][d]*W[e][d] + bias[e]) * scale
// ---------------------------------------------------------------------------
template<bool TRANS>
__global__ __launch_bounds__(256) void proj_kernel(
    const float* __restrict__ A,
    const float* __restrict__ W,
    const float* __restrict__ bias,
    unsigned short* __restrict__ out,
    float scale)
{
    __shared__ __align__(16) short Wlds[256 * 40];

    const int t    = threadIdx.x;
    const int wave = t >> 6, lane = t & 63;
    const int c    = lane & 15, g = lane >> 4;
    const int wrow = blockIdx.x * 64 + wave * 16;

    f32x4 acc[16];
    for (int nt = 0; nt < 16; ++nt) acc[nt] = f32x4{0.f, 0.f, 0.f, 0.f};

    f32x4 wpf[8];
    for (int i = 0; i < 8; ++i) {
        int f = i * 1024 + t * 4;
        wpf[i] = *(const f32x4*)&W[(f >> 5) * 256 + (f & 31)];
    }
    f32x4 a0 = *(const f32x4*)&A[(wrow + c) * 256 + g * 8];
    f32x4 a1 = *(const f32x4*)&A[(wrow + c) * 256 + g * 8 + 4];

    for (int ks = 0; ks < 8; ++ks) {
        __syncthreads();
        for (int i = 0; i < 8; ++i) {
            int f = i * 1024 + t * 4;
            bf16x4 s4;
            s4[0] = f2bf(wpf[i][0]); s4[1] = f2bf(wpf[i][1]);
            s4[2] = f2bf(wpf[i][2]); s4[3] = f2bf(wpf[i][3]);
            *(bf16x4*)&Wlds[(f >> 5) * 40 + (f & 31)] = s4;
        }
        __syncthreads();
        bf16x8 af;
        af[0] = f2bf(a0[0]); af[1] = f2bf(a0[1]); af[2] = f2bf(a0[2]); af[3] = f2bf(a0[3]);
        af[4] = f2bf(a1[0]); af[5] = f2bf(a1[1]); af[6] = f2bf(a1[2]); af[7] = f2bf(a1[3]);
        if (ks < 7) {
            for (int i = 0; i < 8; ++i) {
                int f = i * 1024 + t * 4;
                wpf[i] = *(const f32x4*)&W[(f >> 5) * 256 + (ks + 1) * 32 + (f & 31)];
            }
            a0 = *(const f32x4*)&A[(wrow + c) * 256 + (ks + 1) * 32 + g * 8];
            a1 = *(const f32x4*)&A[(wrow + c) * 256 + (ks + 1) * 32 + g * 8 + 4];
        }
        __builtin_amdgcn_s_setprio(1);
        for (int nt = 0; nt < 16; ++nt) {
            bf16x8 bfr = *(const bf16x8*)&Wlds[(nt * 16 + c) * 40 + g * 8];
            acc[nt] = __builtin_amdgcn_mfma_f32_16x16x32_bf16(af, bfr, acc[nt], 0, 0, 0);
        }
        __builtin_amdgcn_s_setprio(0);
    }

    if constexpr (TRANS) {
        const int nb = wrow >> 12, n0 = wrow & 4095;
        for (int nt = 0; nt < 16; ++nt) {
            float bv = bias[nt * 16 + c];
            bf16x4 s4;
            s4[0] = f2bf((acc[nt][0] + bv) * scale); s4[1] = f2bf((acc[nt][1] + bv) * scale);
            s4[2] = f2bf((acc[nt][2] + bv) * scale); s4[3] = f2bf((acc[nt][3] + bv) * scale);
            *(bf16x4*)&out[((size_t)nb * DIM + nt * 16 + c) * SEQ + n0 + g * 4] = s4;
        }
    } else {
        for (int nt = 0; nt < 16; ++nt) {
            float bv = bias[nt * 16 + c];
            for (int j = 0; j < 4; ++j)
                out[(size_t)(wrow + g * 4 + j) * 256 + nt * 16 + c] =
                    (unsigned short)f2bf((acc[nt][j] + bv) * scale);
        }
    }
}

// ---------------------------------------------------------------------------
// Fused K+V projection: reads z once, produces K (row-major) and Vt (trans).
// ---------------------------------------------------------------------------
__global__ __launch_bounds__(256) void kv_proj_kernel(
    const float* __restrict__ A,     // z [16384][256]
    const float* __restrict__ Wk, const float* __restrict__ bk,
    const float* __restrict__ Wv, const float* __restrict__ bv,
    unsigned short* __restrict__ Kout,   // [4][4096][256]
    unsigned short* __restrict__ Vtout)  // [4][256][4096]
{
    __shared__ __align__(16) short WldsK[256 * 40];
    __shared__ __align__(16) short WldsV[256 * 40];

    const int t    = threadIdx.x;
    const int wave = t >> 6, lane = t & 63;
    const int c    = lane & 15, g = lane >> 4;
    const int wrow = blockIdx.x * 64 + wave * 16;

    f32x4 acck[16], accv[16];
    for (int nt = 0; nt < 16; ++nt) {
        acck[nt] = f32x4{0.f, 0.f, 0.f, 0.f};
        accv[nt] = f32x4{0.f, 0.f, 0.f, 0.f};
    }

    f32x4 wpfk[8], wpfv[8];
    for (int i = 0; i < 8; ++i) {
        int f = i * 1024 + t * 4;
        wpfk[i] = *(const f32x4*)&Wk[(f >> 5) * 256 + (f & 31)];
        wpfv[i] = *(const f32x4*)&Wv[(f >> 5) * 256 + (f & 31)];
    }
    f32x4 a0 = *(const f32x4*)&A[(wrow + c) * 256 + g * 8];
    f32x4 a1 = *(const f32x4*)&A[(wrow + c) * 256 + g * 8 + 4];

    for (int ks = 0; ks < 8; ++ks) {
        __syncthreads();
        for (int i = 0; i < 8; ++i) {
            int f = i * 1024 + t * 4;
            bf16x4 sk, sv;
            sk[0] = f2bf(wpfk[i][0]); sk[1] = f2bf(wpfk[i][1]);
            sk[2] = f2bf(wpfk[i][2]); sk[3] = f2bf(wpfk[i][3]);
            sv[0] = f2bf(wpfv[i][0]); sv[1] = f2bf(wpfv[i][1]);
            sv[2] = f2bf(wpfv[i][2]); sv[3] = f2bf(wpfv[i][3]);
            *(bf16x4*)&WldsK[(f >> 5) * 40 + (f & 31)] = sk;
            *(bf16x4*)&WldsV[(f >> 5) * 40 + (f & 31)] = sv;
        }
        __syncthreads();
        bf16x8 af;
        af[0] = f2bf(a0[0]); af[1] = f2bf(a0[1]); af[2] = f2bf(a0[2]); af[3] = f2bf(a0[3]);
        af[4] = f2bf(a1[0]); af[5] = f2bf(a1[1]); af[6] = f2bf(a1[2]); af[7] = f2bf(a1[3]);
        if (ks < 7) {
            for (int i = 0; i < 8; ++i) {
                int f = i * 1024 + t * 4;
                wpfk[i] = *(const f32x4*)&Wk[(f >> 5) * 256 + (ks + 1) * 32 + (f & 31)];
                wpfv[i] = *(const f32x4*)&Wv[(f >> 5) * 256 + (ks + 1) * 32 + (f & 31)];
            }
            a0 = *(const f32x4*)&A[(wrow + c) * 256 + (ks + 1) * 32 + g * 8];
            a1 = *(const f32x4*)&A[(wrow + c) * 256 + (ks + 1) * 32 + g * 8 + 4];
        }
        __builtin_amdgcn_s_setprio(1);
        for (int nt = 0; nt < 16; ++nt) {
            bf16x8 bk_ = *(const bf16x8*)&WldsK[(nt * 16 + c) * 40 + g * 8];
            acck[nt] = __builtin_amdgcn_mfma_f32_16x16x32_bf16(af, bk_, acck[nt], 0, 0, 0);
            bf16x8 bv_ = *(const bf16x8*)&WldsV[(nt * 16 + c) * 40 + g * 8];
            accv[nt] = __builtin_amdgcn_mfma_f32_16x16x32_bf16(af, bv_, accv[nt], 0, 0, 0);
        }
        __builtin_amdgcn_s_setprio(0);
    }

    // K: row-major
    for (int nt = 0; nt < 16; ++nt) {
        float bb = bk[nt * 16 + c];
        for (int j = 0; j < 4; ++j)
            Kout[(size_t)(wrow + g * 4 + j) * 256 + nt * 16 + c] =
                (unsigned short)f2bf(acck[nt][j] + bb);
    }
    // V: transposed per batch
    const int nb = wrow >> 12, n0 = wrow & 4095;
    for (int nt = 0; nt < 16; ++nt) {
        float bb = bv[nt * 16 + c];
        bf16x4 s4;
        s4[0] = f2bf(accv[nt][0] + bb); s4[1] = f2bf(accv[nt][1] + bb);
        s4[2] = f2bf(accv[nt][2] + bb); s4[3] = f2bf(accv[nt][3] + bb);
        *(bf16x4*)&Vtout[((size_t)nb * DIM + nt * 16 + c) * SEQ + n0 + g * 4] = s4;
    }
}

// ---------------------------------------------------------------------------
// Flash attention (R9 structure, single barrier per tile, base-2 softmax).
// 4 waves x 32 q-rows. KVB=32. gload_lds dbuf. Q pre-scaled by log2e/sqrt(D).
// ---------------------------------------------------------------------------
#define KVB 32

__global__ __launch_bounds__(256, 2) void fa2_kernel(
    const unsigned short* __restrict__ Q,   // bf16, pre-scaled (log2 domain)
    const unsigned short* __restrict__ K,
    const unsigned short* __restrict__ Vt,
    float* __restrict__ Opart,              // [nsplit][4][4096][256] f32
    float2* __restrict__ ml,                // [nsplit][4*4096]  (m in log2 domain)
    int nsplit)
{
    __shared__ __align__(16) unsigned short Klds[2][KVB * 256];
    __shared__ __align__(16) unsigned short Vlds[2][256 * KVB];

    const int t = threadIdx.x;
    const int w = t >> 6, lane = t & 63;
    const int c = lane & 15, g = lane >> 4;

    int b, sidx, qt;
    if (nsplit == 4) {
        int xcd  = blockIdx.x & 7;
        int rest = blockIdx.x >> 3;
        int combo = (xcd << 1) | (rest >> 5);
        qt   = rest & 31;
        b    = combo >> 2;
        sidx = combo & 3;
    } else {
        qt   = blockIdx.x & 31;
        b    = blockIdx.x >> 5;
        sidx = 0;
    }
    const int ts = (sidx * 128) / nsplit;
    const int te = ((sidx + 1) * 128) / nsplit;

    const int wrow = qt * 128 + w * 32;

    bf16x8 qf[2][8];
    #pragma unroll
    for (int h = 0; h < 2; ++h) {
        const unsigned short* Qrow = &Q[((size_t)b * SEQ + wrow + 16 * h + c) * DIM];
        #pragma unroll
        for (int ks = 0; ks < 8; ++ks)
            qf[h][ks] = *(const bf16x8*)&Qrow[ks * 32 + g * 8];
    }

    f32x4 o[2][16];
    #pragma unroll
    for (int h = 0; h < 2; ++h)
        #pragma unroll
        for (int nt = 0; nt < 16; ++nt) o[h][nt] = f32x4{0.f, 0.f, 0.f, 0.f};
    float m[2]     = {-1e30f, -1e30f};
    float llane[2] = {0.f, 0.f};

    const char* Kb_ = (const char*)&K[(size_t)b * SEQ * DIM];
    const char* Vb_ = (const char*)&Vt[(size_t)b * DIM * SEQ];

    const int l31 = lane & 31;
    int koff[4], voff[4], dstb[4];
    const int vsw = ((lane >> 2) & 3) ^ ((lane >> 4) & 3);
    const int vcb = ((lane & 3) ^ vsw) << 4;
    #pragma unroll
    for (int ii = 0; ii < 4; ++ii) {
        int kr = 8 * w + 2 * ii + (lane >> 5);
        int sc = (kr & 3) | ((kr & 8) >> 1);              // sigma_c
        koff[ii] = kr * 512 + ((l31 ^ sc) << 4);
        int vr = 64 * w + 16 * ii + (lane >> 2);
        voff[ii] = vr * (SEQ * 2) + vcb;
        dstb[ii] = (4 * w + ii) * 1024;
    }

    #define STAGE(kt_, buf_) do {                                              \
        const size_t kb_ = (size_t)(kt_) * (KVB * DIM * 2);                    \
        const size_t vb_ = (size_t)(kt_) * (KVB * 2);                          \
        _Pragma("unroll")                                                      \
        for (int ii = 0; ii < 4; ++ii) {                                       \
            gload_lds16(Kb_ + kb_ + koff[ii], (char*)&Klds[buf_][0] + dstb[ii]); \
            gload_lds16(Vb_ + vb_ + voff[ii], (char*)&Vlds[buf_][0] + dstb[ii]); \
        }                                                                      \
    } while (0)

    STAGE(ts, 0);
    int buf = 0;

    const int xk   = (c & 7) << 3;
    const int rphi = ((c & 3) + 8 * (c >> 2));
    const int vcol = (g * 8) ^ ((((c & 3) ^ ((c >> 2) & 3))) << 3);

    for (int kt = ts; kt < te; ++kt) {
        // single barrier: jointly ensures (a) everyone's tile-kt DMA landed
        // (each wave drained its own vmcnt first), (b) everyone finished
        // reading buf^1 (their compute of tile kt-1 precedes this barrier).
        asm volatile("s_waitcnt vmcnt(0)" ::: "memory");
        __builtin_amdgcn_s_barrier();
        if (kt + 1 < te) STAGE(kt + 1, buf ^ 1);   // writes buf^1: safe now

        const unsigned short* Kl = &Klds[buf][0];
        const unsigned short* Vl = &Vlds[buf][0];

        f32x4 s[2][2];
        #pragma unroll
        for (int h = 0; h < 2; ++h) {
            s[h][0] = f32x4{0.f, 0.f, 0.f, 0.f};
            s[h][1] = f32x4{0.f, 0.f, 0.f, 0.f};
        }
        __builtin_amdgcn_s_setprio(1);
        #pragma unroll
        for (int ks = 0; ks < 8; ++ks) {
            int off = (ks * 32 + g * 8) ^ xk;
            bf16x8 kf0 = *(const bf16x8*)&Kl[rphi * 256 + off];
            bf16x8 kf1 = *(const bf16x8*)&Kl[(rphi + 4) * 256 + off];
            s[0][0] = __builtin_amdgcn_mfma_f32_16x16x32_bf16(kf0, qf[0][ks], s[0][0], 0, 0, 0);
            s[1][0] = __builtin_amdgcn_mfma_f32_16x16x32_bf16(kf0, qf[1][ks], s[1][0], 0, 0, 0);
            s[0][1] = __builtin_amdgcn_mfma_f32_16x16x32_bf16(kf1, qf[0][ks], s[0][1], 0, 0, 0);
            s[1][1] = __builtin_amdgcn_mfma_f32_16x16x32_bf16(kf1, qf[1][ks], s[1][1], 0, 0, 0);
        }
        __builtin_amdgcn_s_setprio(0);

        // defer-max softmax in log2 domain (threshold 11 bits ~ 8 nats)
        float pm[2];
        #pragma unroll
        for (int h = 0; h < 2; ++h)
            pm[h] = fmaxf(fmaxf(fmaxf(s[h][0][0], s[h][0][1]), fmaxf(s[h][0][2], s[h][0][3])),
                          fmaxf(fmaxf(s[h][1][0], s[h][1][1]), fmaxf(s[h][1][2], s[h][1][3])));
        bool ok = (pm[0] <= m[0] + 11.f) && (pm[1] <= m[1] + 11.f);
        if (!__all(ok)) {
            #pragma unroll
            for (int h = 0; h < 2; ++h) {
                float pr = pm[h];
                pr = fmaxf(pr, __shfl_xor(pr, 16));
                pr = fmaxf(pr, __shfl_xor(pr, 32));
                float mn = fmaxf(m[h], pr);
                float r  = exp2f(m[h] - mn);
                m[h] = mn; llane[h] *= r;
                float r0 = __shfl(r, g * 4 + 0), r1 = __shfl(r, g * 4 + 1);
                float r2 = __shfl(r, g * 4 + 2), r3 = __shfl(r, g * 4 + 3);
                #pragma unroll
                for (int nt = 0; nt < 16; ++nt) {
                    o[h][nt][0] *= r0; o[h][nt][1] *= r1;
                    o[h][nt][2] *= r2; o[h][nt][3] *= r3;
                }
            }
        }
        bf16x8 pa0, pa1;
        {
            float p0 = exp2f(s[0][0][0] - m[0]), p1 = exp2f(s[0][0][1] - m[0]);
            float p2 = exp2f(s[0][0][2] - m[0]), p3 = exp2f(s[0][0][3] - m[0]);
            float p4 = exp2f(s[0][1][0] - m[0]), p5 = exp2f(s[0][1][1] - m[0]);
            float p6 = exp2f(s[0][1][2] - m[0]), p7 = exp2f(s[0][1][3] - m[0]);
            llane[0] += ((p0 + p1) + (p2 + p3)) + ((p4 + p5) + (p6 + p7));
            pa0[0] = f2bf(p0); pa0[1] = f2bf(p1); pa0[2] = f2bf(p2); pa0[3] = f2bf(p3);
            pa0[4] = f2bf(p4); pa0[5] = f2bf(p5); pa0[6] = f2bf(p6); pa0[7] = f2bf(p7);
        }
        {
            float p0 = exp2f(s[1][0][0] - m[1]), p1 = exp2f(s[1][0][1] - m[1]);
            float p2 = exp2f(s[1][0][2] - m[1]), p3 = exp2f(s[1][0][3] - m[1]);
            float p4 = exp2f(s[1][1][0] - m[1]), p5 = exp2f(s[1][1][1] - m[1]);
            float p6 = exp2f(s[1][1][2] - m[1]), p7 = exp2f(s[1][1][3] - m[1]);
            llane[1] += ((p0 + p1) + (p2 + p3)) + ((p4 + p5) + (p6 + p7));
            pa1[0] = f2bf(p0); pa1[1] = f2bf(p1); pa1[2] = f2bf(p2); pa1[3] = f2bf(p3);
            pa1[4] = f2bf(p4); pa1[5] = f2bf(p5); pa1[6] = f2bf(p6); pa1[7] = f2bf(p7);
        }

        __builtin_amdgcn_s_setprio(1);
        #pragma unroll
        for (int nt = 0; nt < 16; ++nt) {
            bf16x8 vf = *(const bf16x8*)&Vl[(nt * 16 + c) * 32 + vcol];
            o[0][nt] = __builtin_amdgcn_mfma_f32_16x16x32_bf16(pa0, vf, o[0][nt], 0, 0, 0);
            o[1][nt] = __builtin_amdgcn_mfma_f32_16x16x32_bf16(pa1, vf, o[1][nt], 0, 0, 0);
        }
        __builtin_amdgcn_s_setprio(0);
        buf ^= 1;
    }

    #pragma unroll
    for (int h = 0; h < 2; ++h) {
        float lsum = llane[h];
        lsum += __shfl_xor(lsum, 16);
        lsum += __shfl_xor(lsum, 32);
        float inv = 1.0f / lsum;
        float i0 = __shfl(inv, g * 4 + 0), i1 = __shfl(inv, g * 4 + 1);
        float i2 = __shfl(inv, g * 4 + 2), i3 = __shfl(inv, g * 4 + 3);

        const size_t obase = ((size_t)sidx * BATCH * SEQ + (size_t)b * SEQ + wrow + 16 * h) * DIM;
        for (int nt = 0; nt < 16; ++nt) {
            Opart[obase + (size_t)(g * 4 + 0) * DIM + nt * 16 + c] = o[h][nt][0] * i0;
            Opart[obase + (size_t)(g * 4 + 1) * DIM + nt * 16 + c] = o[h][nt][1] * i1;
            Opart[obase + (size_t)(g * 4 + 2) * DIM + nt * 16 + c] = o[h][nt][2] * i2;
            Opart[obase + (size_t)(g * 4 + 3) * DIM + nt * 16 + c] = o[h][nt][3] * i3;
        }
        if (g == 0) {
            ml[(size_t)sidx * BATCH * SEQ + (size_t)b * SEQ + wrow + 16 * h + c] =
                make_float2(m[h], lsum);
        }
    }
}

// ---------------------------------------------------------------------------
// Combine 4 KV-split partials (log2-domain m): w_s = l_s * 2^(m_s - M)
// ---------------------------------------------------------------------------
__global__ __launch_bounds__(256) void combine_kernel(
    const float* __restrict__ Opart, const float2* __restrict__ ml,
    float* __restrict__ out)
{
    const int t = threadIdx.x;
    const size_t row = (size_t)blockIdx.x * 4 + (t >> 6);
    const int lane = t & 63;

    float2 e[4];
    float M = -1e30f;
    for (int s = 0; s < 4; ++s) {
        e[s] = ml[(size_t)s * BATCH * SEQ + row];
        M = fmaxf(M, e[s].x);
    }
    float wgt[4], L = 0.f;
    for (int s = 0; s < 4; ++s) { wgt[s] = e[s].y * exp2f(e[s].x - M); L += wgt[s]; }
    float invL = 1.0f / L;

    f32x4 acc = f32x4{0.f, 0.f, 0.f, 0.f};
    for (int s = 0; s < 4; ++s) {
        f32x4 v = *(const f32x4*)&Opart[((size_t)s * BATCH * SEQ + row) * DIM + lane * 4];
        float ws = wgt[s] * invL;
        acc[0] += ws * v[0]; acc[1] += ws * v[1];
        acc[2] += ws * v[2]; acc[3] += ws * v[3];
    }
    *(f32x4*)&out[row * DIM + lane * 4] = acc;
}

// ---------------------------------------------------------------------------
extern "C" void kernel_launch(void* const* d_in, const int* in_sizes, int n_in,
                              void* d_out, int out_size, void* d_ws, size_t ws_size,
                              hipStream_t stream) {
    const float* x  = (const float*)d_in[0];
    const float* z  = (const float*)d_in[1];
    const float* Wq = (const float*)d_in[2];
    const float* bq = (const float*)d_in[3];
    const float* Wk = (const float*)d_in[4];
    const float* bk = (const float*)d_in[5];
    const float* Wv = (const float*)d_in[6];
    const float* bv = (const float*)d_in[7];
    float* out = (float*)d_out;

    const size_t TENS = (size_t)BATCH * SEQ * DIM;
    unsigned short* Qb  = (unsigned short*)d_ws;
    unsigned short* Kb  = Qb + TENS;
    unsigned short* Vtb = Kb + TENS;

    const size_t base_bytes = 3 * TENS * sizeof(unsigned short);       // 24 MB
    const size_t need4 = base_bytes + 4 * TENS * sizeof(float)         // 64 MB
                       + 4 * (size_t)BATCH * SEQ * sizeof(float2);
    const int nsplit = (ws_size >= need4) ? 4 : 1;

    const float qscale = 0.0625f * LOG2E;  // 1/sqrt(D) * log2(e): base-2 softmax

    proj_kernel<false><<<256, 256, 0, stream>>>(x, Wq, bq, Qb, qscale);
    kv_proj_kernel<<<256, 256, 0, stream>>>(z, Wk, bk, Wv, bv, Kb, Vtb);

    if (nsplit == 4) {
        float*  Op  = (float*)((char*)d_ws + base_bytes);
        float2* mlb = (float2*)((char*)d_ws + base_bytes + 4 * TENS * sizeof(float));
        fa2_kernel<<<512, 256, 0, stream>>>(Qb, Kb, Vtb, Op, mlb, 4);
        combine_kernel<<<4096, 256, 0, stream>>>(Op, mlb, out);
    } else {
        float2* mlb = (float2*)((char*)d_ws + base_bytes);
        fa2_kernel<<<128, 256, 0, stream>>>(Qb, Kb, Vtb, out, mlb, 1);
    }
}

// Round 11
// 140.688 us; speedup vs baseline: 1.1324x; 1.1324x over previous
//
#include <hip/hip_runtime.h>
#include <hip/hip_bf16.h>
#include <math.h>

#define BATCH 4
#define SEQ   4096
#define DIM   256
#define AS1 __attribute__((address_space(1)))
#define AS3 __attribute__((address_space(3)))

typedef __attribute__((ext_vector_type(8))) short  bf16x8;
typedef __attribute__((ext_vector_type(4))) short  bf16x4;
typedef __attribute__((ext_vector_type(4))) float  f32x4;
typedef __attribute__((ext_vector_type(4))) int    i32x4;

#define LOG2E 1.44269504088896340736f
#define EXP2(x) __builtin_amdgcn_exp2f(x)   // raw v_exp_f32 (2^x), 1 instr

__device__ __forceinline__ short f2bf(float f) {
    union { float f; unsigned u; } v; v.f = f;
    unsigned r = (v.u + 0x7fffu + ((v.u >> 16) & 1u)) >> 16;
    return (short)r;
}

__device__ __forceinline__ void gload_lds16(const void* g, void* l) {
    __builtin_amdgcn_global_load_lds((const AS1 void*)g, (AS3 void*)l, 16, 0, 0);
}

// ---------------------------------------------------------------------------
// Projection (single): out[n][e] = (sum_d A[n][d]*W[e][d] + bias[e]) * scale
// ---------------------------------------------------------------------------
template<bool TRANS>
__global__ __launch_bounds__(256) void proj_kernel(
    const float* __restrict__ A,
    const float* __restrict__ W,
    const float* __restrict__ bias,
    unsigned short* __restrict__ out,
    float scale)
{
    __shared__ __align__(16) short Wlds[256 * 40];

    const int t    = threadIdx.x;
    const int wave = t >> 6, lane = t & 63;
    const int c    = lane & 15, g = lane >> 4;
    const int wrow = blockIdx.x * 64 + wave * 16;

    f32x4 acc[16];
    for (int nt = 0; nt < 16; ++nt) acc[nt] = f32x4{0.f, 0.f, 0.f, 0.f};

    f32x4 wpf[8];
    for (int i = 0; i < 8; ++i) {
        int f = i * 1024 + t * 4;
        wpf[i] = *(const f32x4*)&W[(f >> 5) * 256 + (f & 31)];
    }
    f32x4 a0 = *(const f32x4*)&A[(wrow + c) * 256 + g * 8];
    f32x4 a1 = *(const f32x4*)&A[(wrow + c) * 256 + g * 8 + 4];

    for (int ks = 0; ks < 8; ++ks) {
        __syncthreads();
        for (int i = 0; i < 8; ++i) {
            int f = i * 1024 + t * 4;
            bf16x4 s4;
            s4[0] = f2bf(wpf[i][0]); s4[1] = f2bf(wpf[i][1]);
            s4[2] = f2bf(wpf[i][2]); s4[3] = f2bf(wpf[i][3]);
            *(bf16x4*)&Wlds[(f >> 5) * 40 + (f & 31)] = s4;
        }
        __syncthreads();
        bf16x8 af;
        af[0] = f2bf(a0[0]); af[1] = f2bf(a0[1]); af[2] = f2bf(a0[2]); af[3] = f2bf(a0[3]);
        af[4] = f2bf(a1[0]); af[5] = f2bf(a1[1]); af[6] = f2bf(a1[2]); af[7] = f2bf(a1[3]);
        if (ks < 7) {
            for (int i = 0; i < 8; ++i) {
                int f = i * 1024 + t * 4;
                wpf[i] = *(const f32x4*)&W[(f >> 5) * 256 + (ks + 1) * 32 + (f & 31)];
            }
            a0 = *(const f32x4*)&A[(wrow + c) * 256 + (ks + 1) * 32 + g * 8];
            a1 = *(const f32x4*)&A[(wrow + c) * 256 + (ks + 1) * 32 + g * 8 + 4];
        }
        __builtin_amdgcn_s_setprio(1);
        for (int nt = 0; nt < 16; ++nt) {
            bf16x8 bfr = *(const bf16x8*)&Wlds[(nt * 16 + c) * 40 + g * 8];
            acc[nt] = __builtin_amdgcn_mfma_f32_16x16x32_bf16(af, bfr, acc[nt], 0, 0, 0);
        }
        __builtin_amdgcn_s_setprio(0);
    }

    if constexpr (TRANS) {
        const int nb = wrow >> 12, n0 = wrow & 4095;
        for (int nt = 0; nt < 16; ++nt) {
            float bv = bias[nt * 16 + c];
            bf16x4 s4;
            s4[0] = f2bf((acc[nt][0] + bv) * scale); s4[1] = f2bf((acc[nt][1] + bv) * scale);
            s4[2] = f2bf((acc[nt][2] + bv) * scale); s4[3] = f2bf((acc[nt][3] + bv) * scale);
            *(bf16x4*)&out[((size_t)nb * DIM + nt * 16 + c) * SEQ + n0 + g * 4] = s4;
        }
    } else {
        for (int nt = 0; nt < 16; ++nt) {
            float bv = bias[nt * 16 + c];
            for (int j = 0; j < 4; ++j)
                out[(size_t)(wrow + g * 4 + j) * 256 + nt * 16 + c] =
                    (unsigned short)f2bf((acc[nt][j] + bv) * scale);
        }
    }
}

// ---------------------------------------------------------------------------
// Fused K+V projection: reads z once, produces K (row-major) and Vt (trans).
// ---------------------------------------------------------------------------
__global__ __launch_bounds__(256) void kv_proj_kernel(
    const float* __restrict__ A,     // z [16384][256]
    const float* __restrict__ Wk, const float* __restrict__ bk,
    const float* __restrict__ Wv, const float* __restrict__ bv,
    unsigned short* __restrict__ Kout,   // [4][4096][256]
    unsigned short* __restrict__ Vtout)  // [4][256][4096]
{
    __shared__ __align__(16) short WldsK[256 * 40];
    __shared__ __align__(16) short WldsV[256 * 40];

    const int t    = threadIdx.x;
    const int wave = t >> 6, lane = t & 63;
    const int c    = lane & 15, g = lane >> 4;
    const int wrow = blockIdx.x * 64 + wave * 16;

    f32x4 acck[16], accv[16];
    for (int nt = 0; nt < 16; ++nt) {
        acck[nt] = f32x4{0.f, 0.f, 0.f, 0.f};
        accv[nt] = f32x4{0.f, 0.f, 0.f, 0.f};
    }

    f32x4 wpfk[8], wpfv[8];
    for (int i = 0; i < 8; ++i) {
        int f = i * 1024 + t * 4;
        wpfk[i] = *(const f32x4*)&Wk[(f >> 5) * 256 + (f & 31)];
        wpfv[i] = *(const f32x4*)&Wv[(f >> 5) * 256 + (f & 31)];
    }
    f32x4 a0 = *(const f32x4*)&A[(wrow + c) * 256 + g * 8];
    f32x4 a1 = *(const f32x4*)&A[(wrow + c) * 256 + g * 8 + 4];

    for (int ks = 0; ks < 8; ++ks) {
        __syncthreads();
        for (int i = 0; i < 8; ++i) {
            int f = i * 1024 + t * 4;
            bf16x4 sk, sv;
            sk[0] = f2bf(wpfk[i][0]); sk[1] = f2bf(wpfk[i][1]);
            sk[2] = f2bf(wpfk[i][2]); sk[3] = f2bf(wpfk[i][3]);
            sv[0] = f2bf(wpfv[i][0]); sv[1] = f2bf(wpfv[i][1]);
            sv[2] = f2bf(wpfv[i][2]); sv[3] = f2bf(wpfv[i][3]);
            *(bf16x4*)&WldsK[(f >> 5) * 40 + (f & 31)] = sk;
            *(bf16x4*)&WldsV[(f >> 5) * 40 + (f & 31)] = sv;
        }
        __syncthreads();
        bf16x8 af;
        af[0] = f2bf(a0[0]); af[1] = f2bf(a0[1]); af[2] = f2bf(a0[2]); af[3] = f2bf(a0[3]);
        af[4] = f2bf(a1[0]); af[5] = f2bf(a1[1]); af[6] = f2bf(a1[2]); af[7] = f2bf(a1[3]);
        if (ks < 7) {
            for (int i = 0; i < 8; ++i) {
                int f = i * 1024 + t * 4;
                wpfk[i] = *(const f32x4*)&Wk[(f >> 5) * 256 + (ks + 1) * 32 + (f & 31)];
                wpfv[i] = *(const f32x4*)&Wv[(f >> 5) * 256 + (ks + 1) * 32 + (f & 31)];
            }
            a0 = *(const f32x4*)&A[(wrow + c) * 256 + (ks + 1) * 32 + g * 8];
            a1 = *(const f32x4*)&A[(wrow + c) * 256 + (ks + 1) * 32 + g * 8 + 4];
        }
        __builtin_amdgcn_s_setprio(1);
        for (int nt = 0; nt < 16; ++nt) {
            bf16x8 bk_ = *(const bf16x8*)&WldsK[(nt * 16 + c) * 40 + g * 8];
            acck[nt] = __builtin_amdgcn_mfma_f32_16x16x32_bf16(af, bk_, acck[nt], 0, 0, 0);
            bf16x8 bv_ = *(const bf16x8*)&WldsV[(nt * 16 + c) * 40 + g * 8];
            accv[nt] = __builtin_amdgcn_mfma_f32_16x16x32_bf16(af, bv_, accv[nt], 0, 0, 0);
        }
        __builtin_amdgcn_s_setprio(0);
    }

    // K: row-major
    for (int nt = 0; nt < 16; ++nt) {
        float bb = bk[nt * 16 + c];
        for (int j = 0; j < 4; ++j)
            Kout[(size_t)(wrow + g * 4 + j) * 256 + nt * 16 + c] =
                (unsigned short)f2bf(acck[nt][j] + bb);
    }
    // V: transposed per batch
    const int nb = wrow >> 12, n0 = wrow & 4095;
    for (int nt = 0; nt < 16; ++nt) {
        float bb = bv[nt * 16 + c];
        bf16x4 s4;
        s4[0] = f2bf(accv[nt][0] + bb); s4[1] = f2bf(accv[nt][1] + bb);
        s4[2] = f2bf(accv[nt][2] + bb); s4[3] = f2bf(accv[nt][3] + bb);
        *(bf16x4*)&Vtout[((size_t)nb * DIM + nt * 16 + c) * SEQ + n0 + g * 4] = s4;
    }
}

// ---------------------------------------------------------------------------
// Flash attention: R9 sync structure (double barrier + vmcnt(8)),
// base-2 softmax with raw v_exp_f32. 4 waves x 32 q-rows, KVB=32.
// Q pre-scaled by log2e/sqrt(D).
// ---------------------------------------------------------------------------
#define KVB 32

__global__ __launch_bounds__(256, 2) void fa2_kernel(
    const unsigned short* __restrict__ Q,   // bf16, pre-scaled (log2 domain)
    const unsigned short* __restrict__ K,
    const unsigned short* __restrict__ Vt,
    float* __restrict__ Opart,              // [nsplit][4][4096][256] f32
    float2* __restrict__ ml,                // [nsplit][4*4096]  (m in log2 domain)
    int nsplit)
{
    __shared__ __align__(16) unsigned short Klds[2][KVB * 256];
    __shared__ __align__(16) unsigned short Vlds[2][256 * KVB];

    const int t = threadIdx.x;
    const int w = t >> 6, lane = t & 63;
    const int c = lane & 15, g = lane >> 4;

    int b, sidx, qt;
    if (nsplit == 4) {
        int xcd  = blockIdx.x & 7;
        int rest = blockIdx.x >> 3;
        int combo = (xcd << 1) | (rest >> 5);
        qt   = rest & 31;
        b    = combo >> 2;
        sidx = combo & 3;
    } else {
        qt   = blockIdx.x & 31;
        b    = blockIdx.x >> 5;
        sidx = 0;
    }
    const int ts = (sidx * 128) / nsplit;
    const int te = ((sidx + 1) * 128) / nsplit;

    const int wrow = qt * 128 + w * 32;

    bf16x8 qf[2][8];
    #pragma unroll
    for (int h = 0; h < 2; ++h) {
        const unsigned short* Qrow = &Q[((size_t)b * SEQ + wrow + 16 * h + c) * DIM];
        #pragma unroll
        for (int ks = 0; ks < 8; ++ks)
            qf[h][ks] = *(const bf16x8*)&Qrow[ks * 32 + g * 8];
    }

    f32x4 o[2][16];
    #pragma unroll
    for (int h = 0; h < 2; ++h)
        #pragma unroll
        for (int nt = 0; nt < 16; ++nt) o[h][nt] = f32x4{0.f, 0.f, 0.f, 0.f};
    float m[2]     = {-1e30f, -1e30f};
    float llane[2] = {0.f, 0.f};

    const char* Kb_ = (const char*)&K[(size_t)b * SEQ * DIM];
    const char* Vb_ = (const char*)&Vt[(size_t)b * DIM * SEQ];

    const int l31 = lane & 31;
    int koff[4], voff[4], dstb[4];
    const int vsw = ((lane >> 2) & 3) ^ ((lane >> 4) & 3);
    const int vcb = ((lane & 3) ^ vsw) << 4;
    #pragma unroll
    for (int ii = 0; ii < 4; ++ii) {
        int kr = 8 * w + 2 * ii + (lane >> 5);
        int sc = (kr & 3) | ((kr & 8) >> 1);              // sigma_c
        koff[ii] = kr * 512 + ((l31 ^ sc) << 4);
        int vr = 64 * w + 16 * ii + (lane >> 2);
        voff[ii] = vr * (SEQ * 2) + vcb;
        dstb[ii] = (4 * w + ii) * 1024;
    }

    #define STAGE(kt_, buf_) do {                                              \
        const size_t kb_ = (size_t)(kt_) * (KVB * DIM * 2);                    \
        const size_t vb_ = (size_t)(kt_) * (KVB * 2);                          \
        _Pragma("unroll")                                                      \
        for (int ii = 0; ii < 4; ++ii) {                                       \
            gload_lds16(Kb_ + kb_ + koff[ii], (char*)&Klds[buf_][0] + dstb[ii]); \
            gload_lds16(Vb_ + vb_ + voff[ii], (char*)&Vlds[buf_][0] + dstb[ii]); \
        }                                                                      \
    } while (0)

    STAGE(ts, 0);
    int buf = 0;

    const int xk   = (c & 7) << 3;
    const int rphi = ((c & 3) + 8 * (c >> 2));
    const int vcol = (g * 8) ^ ((((c & 3) ^ ((c >> 2) & 3))) << 3);

    for (int kt = ts; kt < te; ++kt) {
        __builtin_amdgcn_s_barrier();   // all waves done reading buf^1
        if (kt + 1 < te) {
            STAGE(kt + 1, buf ^ 1);
            asm volatile("s_waitcnt vmcnt(8)" ::: "memory");  // tile kt landed
        } else {
            asm volatile("s_waitcnt vmcnt(0)" ::: "memory");
        }
        __builtin_amdgcn_s_barrier();   // tile kt visible to all waves

        const unsigned short* Kl = &Klds[buf][0];
        const unsigned short* Vl = &Vlds[buf][0];

        f32x4 s[2][2];
        #pragma unroll
        for (int h = 0; h < 2; ++h) {
            s[h][0] = f32x4{0.f, 0.f, 0.f, 0.f};
            s[h][1] = f32x4{0.f, 0.f, 0.f, 0.f};
        }
        __builtin_amdgcn_s_setprio(1);
        #pragma unroll
        for (int ks = 0; ks < 8; ++ks) {
            int off = (ks * 32 + g * 8) ^ xk;
            bf16x8 kf0 = *(const bf16x8*)&Kl[rphi * 256 + off];
            bf16x8 kf1 = *(const bf16x8*)&Kl[(rphi + 4) * 256 + off];
            s[0][0] = __builtin_amdgcn_mfma_f32_16x16x32_bf16(kf0, qf[0][ks], s[0][0], 0, 0, 0);
            s[1][0] = __builtin_amdgcn_mfma_f32_16x16x32_bf16(kf0, qf[1][ks], s[1][0], 0, 0, 0);
            s[0][1] = __builtin_amdgcn_mfma_f32_16x16x32_bf16(kf1, qf[0][ks], s[0][1], 0, 0, 0);
            s[1][1] = __builtin_amdgcn_mfma_f32_16x16x32_bf16(kf1, qf[1][ks], s[1][1], 0, 0, 0);
        }
        __builtin_amdgcn_s_setprio(0);

        // defer-max softmax in log2 domain (threshold 11 bits ~ 8 nats)
        float pm[2];
        #pragma unroll
        for (int h = 0; h < 2; ++h)
            pm[h] = fmaxf(fmaxf(fmaxf(s[h][0][0], s[h][0][1]), fmaxf(s[h][0][2], s[h][0][3])),
                          fmaxf(fmaxf(s[h][1][0], s[h][1][1]), fmaxf(s[h][1][2], s[h][1][3])));
        bool ok = (pm[0] <= m[0] + 11.f) && (pm[1] <= m[1] + 11.f);
        if (!__all(ok)) {
            #pragma unroll
            for (int h = 0; h < 2; ++h) {
                float pr = pm[h];
                pr = fmaxf(pr, __shfl_xor(pr, 16));
                pr = fmaxf(pr, __shfl_xor(pr, 32));
                float mn = fmaxf(m[h], pr);
                float r  = EXP2(m[h] - mn);
                m[h] = mn; llane[h] *= r;
                float r0 = __shfl(r, g * 4 + 0), r1 = __shfl(r, g * 4 + 1);
                float r2 = __shfl(r, g * 4 + 2), r3 = __shfl(r, g * 4 + 3);
                #pragma unroll
                for (int nt = 0; nt < 16; ++nt) {
                    o[h][nt][0] *= r0; o[h][nt][1] *= r1;
                    o[h][nt][2] *= r2; o[h][nt][3] *= r3;
                }
            }
        }
        bf16x8 pa0, pa1;
        {
            float p0 = EXP2(s[0][0][0] - m[0]), p1 = EXP2(s[0][0][1] - m[0]);
            float p2 = EXP2(s[0][0][2] - m[0]), p3 = EXP2(s[0][0][3] - m[0]);
            float p4 = EXP2(s[0][1][0] - m[0]), p5 = EXP2(s[0][1][1] - m[0]);
            float p6 = EXP2(s[0][1][2] - m[0]), p7 = EXP2(s[0][1][3] - m[0]);
            llane[0] += ((p0 + p1) + (p2 + p3)) + ((p4 + p5) + (p6 + p7));
            pa0[0] = f2bf(p0); pa0[1] = f2bf(p1); pa0[2] = f2bf(p2); pa0[3] = f2bf(p3);
            pa0[4] = f2bf(p4); pa0[5] = f2bf(p5); pa0[6] = f2bf(p6); pa0[7] = f2bf(p7);
        }
        {
            float p0 = EXP2(s[1][0][0] - m[1]), p1 = EXP2(s[1][0][1] - m[1]);
            float p2 = EXP2(s[1][0][2] - m[1]), p3 = EXP2(s[1][0][3] - m[1]);
            float p4 = EXP2(s[1][1][0] - m[1]), p5 = EXP2(s[1][1][1] - m[1]);
            float p6 = EXP2(s[1][1][2] - m[1]), p7 = EXP2(s[1][1][3] - m[1]);
            llane[1] += ((p0 + p1) + (p2 + p3)) + ((p4 + p5) + (p6 + p7));
            pa1[0] = f2bf(p0); pa1[1] = f2bf(p1); pa1[2] = f2bf(p2); pa1[3] = f2bf(p3);
            pa1[4] = f2bf(p4); pa1[5] = f2bf(p5); pa1[6] = f2bf(p6); pa1[7] = f2bf(p7);
        }

        __builtin_amdgcn_s_setprio(1);
        #pragma unroll
        for (int nt = 0; nt < 16; ++nt) {
            bf16x8 vf = *(const bf16x8*)&Vl[(nt * 16 + c) * 32 + vcol];
            o[0][nt] = __builtin_amdgcn_mfma_f32_16x16x32_bf16(pa0, vf, o[0][nt], 0, 0, 0);
            o[1][nt] = __builtin_amdgcn_mfma_f32_16x16x32_bf16(pa1, vf, o[1][nt], 0, 0, 0);
        }
        __builtin_amdgcn_s_setprio(0);
        buf ^= 1;
    }

    #pragma unroll
    for (int h = 0; h < 2; ++h) {
        float lsum = llane[h];
        lsum += __shfl_xor(lsum, 16);
        lsum += __shfl_xor(lsum, 32);
        float inv = 1.0f / lsum;
        float i0 = __shfl(inv, g * 4 + 0), i1 = __shfl(inv, g * 4 + 1);
        float i2 = __shfl(inv, g * 4 + 2), i3 = __shfl(inv, g * 4 + 3);

        const size_t obase = ((size_t)sidx * BATCH * SEQ + (size_t)b * SEQ + wrow + 16 * h) * DIM;
        for (int nt = 0; nt < 16; ++nt) {
            Opart[obase + (size_t)(g * 4 + 0) * DIM + nt * 16 + c] = o[h][nt][0] * i0;
            Opart[obase + (size_t)(g * 4 + 1) * DIM + nt * 16 + c] = o[h][nt][1] * i1;
            Opart[obase + (size_t)(g * 4 + 2) * DIM + nt * 16 + c] = o[h][nt][2] * i2;
            Opart[obase + (size_t)(g * 4 + 3) * DIM + nt * 16 + c] = o[h][nt][3] * i3;
        }
        if (g == 0) {
            ml[(size_t)sidx * BATCH * SEQ + (size_t)b * SEQ + wrow + 16 * h + c] =
                make_float2(m[h], lsum);
        }
    }
}

// ---------------------------------------------------------------------------
// Combine 4 KV-split partials (log2-domain m): w_s = l_s * 2^(m_s - M)
// ---------------------------------------------------------------------------
__global__ __launch_bounds__(256) void combine_kernel(
    const float* __restrict__ Opart, const float2* __restrict__ ml,
    float* __restrict__ out)
{
    const int t = threadIdx.x;
    const size_t row = (size_t)blockIdx.x * 4 + (t >> 6);
    const int lane = t & 63;

    float2 e[4];
    float M = -1e30f;
    for (int s = 0; s < 4; ++s) {
        e[s] = ml[(size_t)s * BATCH * SEQ + row];
        M = fmaxf(M, e[s].x);
    }
    float wgt[4], L = 0.f;
    for (int s = 0; s < 4; ++s) { wgt[s] = e[s].y * EXP2(e[s].x - M); L += wgt[s]; }
    float invL = 1.0f / L;

    f32x4 acc = f32x4{0.f, 0.f, 0.f, 0.f};
    for (int s = 0; s < 4; ++s) {
        f32x4 v = *(const f32x4*)&Opart[((size_t)s * BATCH * SEQ + row) * DIM + lane * 4];
        float ws = wgt[s] * invL;
        acc[0] += ws * v[0]; acc[1] += ws * v[1];
        acc[2] += ws * v[2]; acc[3] += ws * v[3];
    }
    *(f32x4*)&out[row * DIM + lane * 4] = acc;
}

// ---------------------------------------------------------------------------
extern "C" void kernel_launch(void* const* d_in, const int* in_sizes, int n_in,
                              void* d_out, int out_size, void* d_ws, size_t ws_size,
                              hipStream_t stream) {
    const float* x  = (const float*)d_in[0];
    const float* z  = (const float*)d_in[1];
    const float* Wq = (const float*)d_in[2];
    const float* bq = (const float*)d_in[3];
    const float* Wk = (const float*)d_in[4];
    const float* bk = (const float*)d_in[5];
    const float* Wv = (const float*)d_in[6];
    const float* bv = (const float*)d_in[7];
    float* out = (float*)d_out;

    const size_t TENS = (size_t)BATCH * SEQ * DIM;
    unsigned short* Qb  = (unsigned short*)d_ws;
    unsigned short* Kb  = Qb + TENS;
    unsigned short* Vtb = Kb + TENS;

    const size_t base_bytes = 3 * TENS * sizeof(unsigned short);       // 24 MB
    const size_t need4 = base_bytes + 4 * TENS * sizeof(float)         // 64 MB
                       + 4 * (size_t)BATCH * SEQ * sizeof(float2);
    const int nsplit = (ws_size >= need4) ? 4 : 1;

    const float qscale = 0.0625f * LOG2E;  // 1/sqrt(D) * log2(e): base-2 softmax

    proj_kernel<false><<<256, 256, 0, stream>>>(x, Wq, bq, Qb, qscale);
    kv_proj_kernel<<<256, 256, 0, stream>>>(z, Wk, bk, Wv, bv, Kb, Vtb);

    if (nsplit == 4) {
        float*  Op  = (float*)((char*)d_ws + base_bytes);
        float2* mlb = (float2*)((char*)d_ws + base_bytes + 4 * TENS * sizeof(float));
        fa2_kernel<<<512, 256, 0, stream>>>(Qb, Kb, Vtb, Op, mlb, 4);
        combine_kernel<<<4096, 256, 0, stream>>>(Op, mlb, out);
    } else {
        float2* mlb = (float2*)((char*)d_ws + base_bytes);
        fa2_kernel<<<128, 256, 0, stream>>>(Qb, Kb, Vtb, out, mlb, 1);
    }
}

// Round 12
// 134.109 us; speedup vs baseline: 1.1879x; 1.0491x over previous
//
#include <hip/hip_runtime.h>
#include <hip/hip_bf16.h>
#include <math.h>

#define BATCH 4
#define SEQ   4096
#define DIM   256
#define AS1 __attribute__((address_space(1)))
#define AS3 __attribute__((address_space(3)))

typedef __attribute__((ext_vector_type(8))) short  bf16x8;
typedef __attribute__((ext_vector_type(4))) short  bf16x4;
typedef __attribute__((ext_vector_type(4))) float  f32x4;
typedef __attribute__((ext_vector_type(4))) int    i32x4;

#define LOG2E 1.44269504088896340736f
#define EXP2(x) __builtin_amdgcn_exp2f(x)   // raw v_exp_f32 (2^x), 1 instr

__device__ __forceinline__ short f2bf(float f) {
    union { float f; unsigned u; } v; v.f = f;
    unsigned r = (v.u + 0x7fffu + ((v.u >> 16) & 1u)) >> 16;
    return (short)r;
}

// pack two f32 -> one dword of 2 bf16 (RTNE), single instruction
__device__ __forceinline__ int cvtpk(float lo, float hi) {
    int r;
    asm("v_cvt_pk_bf16_f32 %0, %1, %2" : "=v"(r) : "v"(lo), "v"(hi));
    return r;
}

__device__ __forceinline__ void gload_lds16(const void* g, void* l) {
    __builtin_amdgcn_global_load_lds((const AS1 void*)g, (AS3 void*)l, 16, 0, 0);
}

// ---------------------------------------------------------------------------
// Projection (single): out[n][e] = (sum_d A[n][d]*W[e][d] + bias[e]) * scale
// ---------------------------------------------------------------------------
template<bool TRANS>
__global__ __launch_bounds__(256) void proj_kernel(
    const float* __restrict__ A,
    const float* __restrict__ W,
    const float* __restrict__ bias,
    unsigned short* __restrict__ out,
    float scale)
{
    __shared__ __align__(16) short Wlds[256 * 40];

    const int t    = threadIdx.x;
    const int wave = t >> 6, lane = t & 63;
    const int c    = lane & 15, g = lane >> 4;
    const int wrow = blockIdx.x * 64 + wave * 16;

    f32x4 acc[16];
    for (int nt = 0; nt < 16; ++nt) acc[nt] = f32x4{0.f, 0.f, 0.f, 0.f};

    f32x4 wpf[8];
    for (int i = 0; i < 8; ++i) {
        int f = i * 1024 + t * 4;
        wpf[i] = *(const f32x4*)&W[(f >> 5) * 256 + (f & 31)];
    }
    f32x4 a0 = *(const f32x4*)&A[(wrow + c) * 256 + g * 8];
    f32x4 a1 = *(const f32x4*)&A[(wrow + c) * 256 + g * 8 + 4];

    for (int ks = 0; ks < 8; ++ks) {
        __syncthreads();
        for (int i = 0; i < 8; ++i) {
            int f = i * 1024 + t * 4;
            bf16x4 s4;
            s4[0] = f2bf(wpf[i][0]); s4[1] = f2bf(wpf[i][1]);
            s4[2] = f2bf(wpf[i][2]); s4[3] = f2bf(wpf[i][3]);
            *(bf16x4*)&Wlds[(f >> 5) * 40 + (f & 31)] = s4;
        }
        __syncthreads();
        bf16x8 af;
        af[0] = f2bf(a0[0]); af[1] = f2bf(a0[1]); af[2] = f2bf(a0[2]); af[3] = f2bf(a0[3]);
        af[4] = f2bf(a1[0]); af[5] = f2bf(a1[1]); af[6] = f2bf(a1[2]); af[7] = f2bf(a1[3]);
        if (ks < 7) {
            for (int i = 0; i < 8; ++i) {
                int f = i * 1024 + t * 4;
                wpf[i] = *(const f32x4*)&W[(f >> 5) * 256 + (ks + 1) * 32 + (f & 31)];
            }
            a0 = *(const f32x4*)&A[(wrow + c) * 256 + (ks + 1) * 32 + g * 8];
            a1 = *(const f32x4*)&A[(wrow + c) * 256 + (ks + 1) * 32 + g * 8 + 4];
        }
        __builtin_amdgcn_s_setprio(1);
        for (int nt = 0; nt < 16; ++nt) {
            bf16x8 bfr = *(const bf16x8*)&Wlds[(nt * 16 + c) * 40 + g * 8];
            acc[nt] = __builtin_amdgcn_mfma_f32_16x16x32_bf16(af, bfr, acc[nt], 0, 0, 0);
        }
        __builtin_amdgcn_s_setprio(0);
    }

    if constexpr (TRANS) {
        const int nb = wrow >> 12, n0 = wrow & 4095;
        for (int nt = 0; nt < 16; ++nt) {
            float bv = bias[nt * 16 + c];
            bf16x4 s4;
            s4[0] = f2bf((acc[nt][0] + bv) * scale); s4[1] = f2bf((acc[nt][1] + bv) * scale);
            s4[2] = f2bf((acc[nt][2] + bv) * scale); s4[3] = f2bf((acc[nt][3] + bv) * scale);
            *(bf16x4*)&out[((size_t)nb * DIM + nt * 16 + c) * SEQ + n0 + g * 4] = s4;
        }
    } else {
        for (int nt = 0; nt < 16; ++nt) {
            float bv = bias[nt * 16 + c];
            for (int j = 0; j < 4; ++j)
                out[(size_t)(wrow + g * 4 + j) * 256 + nt * 16 + c] =
                    (unsigned short)f2bf((acc[nt][j] + bv) * scale);
        }
    }
}

// ---------------------------------------------------------------------------
// Fused K+V projection: reads z once, produces K (row-major) and Vt (trans).
// ---------------------------------------------------------------------------
__global__ __launch_bounds__(256) void kv_proj_kernel(
    const float* __restrict__ A,     // z [16384][256]
    const float* __restrict__ Wk, const float* __restrict__ bk,
    const float* __restrict__ Wv, const float* __restrict__ bv,
    unsigned short* __restrict__ Kout,   // [4][4096][256]
    unsigned short* __restrict__ Vtout)  // [4][256][4096]
{
    __shared__ __align__(16) short WldsK[256 * 40];
    __shared__ __align__(16) short WldsV[256 * 40];

    const int t    = threadIdx.x;
    const int wave = t >> 6, lane = t & 63;
    const int c    = lane & 15, g = lane >> 4;
    const int wrow = blockIdx.x * 64 + wave * 16;

    f32x4 acck[16], accv[16];
    for (int nt = 0; nt < 16; ++nt) {
        acck[nt] = f32x4{0.f, 0.f, 0.f, 0.f};
        accv[nt] = f32x4{0.f, 0.f, 0.f, 0.f};
    }

    f32x4 wpfk[8], wpfv[8];
    for (int i = 0; i < 8; ++i) {
        int f = i * 1024 + t * 4;
        wpfk[i] = *(const f32x4*)&Wk[(f >> 5) * 256 + (f & 31)];
        wpfv[i] = *(const f32x4*)&Wv[(f >> 5) * 256 + (f & 31)];
    }
    f32x4 a0 = *(const f32x4*)&A[(wrow + c) * 256 + g * 8];
    f32x4 a1 = *(const f32x4*)&A[(wrow + c) * 256 + g * 8 + 4];

    for (int ks = 0; ks < 8; ++ks) {
        __syncthreads();
        for (int i = 0; i < 8; ++i) {
            int f = i * 1024 + t * 4;
            bf16x4 sk, sv;
            sk[0] = f2bf(wpfk[i][0]); sk[1] = f2bf(wpfk[i][1]);
            sk[2] = f2bf(wpfk[i][2]); sk[3] = f2bf(wpfk[i][3]);
            sv[0] = f2bf(wpfv[i][0]); sv[1] = f2bf(wpfv[i][1]);
            sv[2] = f2bf(wpfv[i][2]); sv[3] = f2bf(wpfv[i][3]);
            *(bf16x4*)&WldsK[(f >> 5) * 40 + (f & 31)] = sk;
            *(bf16x4*)&WldsV[(f >> 5) * 40 + (f & 31)] = sv;
        }
        __syncthreads();
        bf16x8 af;
        af[0] = f2bf(a0[0]); af[1] = f2bf(a0[1]); af[2] = f2bf(a0[2]); af[3] = f2bf(a0[3]);
        af[4] = f2bf(a1[0]); af[5] = f2bf(a1[1]); af[6] = f2bf(a1[2]); af[7] = f2bf(a1[3]);
        if (ks < 7) {
            for (int i = 0; i < 8; ++i) {
                int f = i * 1024 + t * 4;
                wpfk[i] = *(const f32x4*)&Wk[(f >> 5) * 256 + (ks + 1) * 32 + (f & 31)];
                wpfv[i] = *(const f32x4*)&Wv[(f >> 5) * 256 + (ks + 1) * 32 + (f & 31)];
            }
            a0 = *(const f32x4*)&A[(wrow + c) * 256 + (ks + 1) * 32 + g * 8];
            a1 = *(const f32x4*)&A[(wrow + c) * 256 + (ks + 1) * 32 + g * 8 + 4];
        }
        __builtin_amdgcn_s_setprio(1);
        for (int nt = 0; nt < 16; ++nt) {
            bf16x8 bk_ = *(const bf16x8*)&WldsK[(nt * 16 + c) * 40 + g * 8];
            acck[nt] = __builtin_amdgcn_mfma_f32_16x16x32_bf16(af, bk_, acck[nt], 0, 0, 0);
            bf16x8 bv_ = *(const bf16x8*)&WldsV[(nt * 16 + c) * 40 + g * 8];
            accv[nt] = __builtin_amdgcn_mfma_f32_16x16x32_bf16(af, bv_, accv[nt], 0, 0, 0);
        }
        __builtin_amdgcn_s_setprio(0);
    }

    // K: row-major
    for (int nt = 0; nt < 16; ++nt) {
        float bb = bk[nt * 16 + c];
        for (int j = 0; j < 4; ++j)
            Kout[(size_t)(wrow + g * 4 + j) * 256 + nt * 16 + c] =
                (unsigned short)f2bf(acck[nt][j] + bb);
    }
    // V: transposed per batch
    const int nb = wrow >> 12, n0 = wrow & 4095;
    for (int nt = 0; nt < 16; ++nt) {
        float bb = bv[nt * 16 + c];
        bf16x4 s4;
        s4[0] = f2bf(accv[nt][0] + bb); s4[1] = f2bf(accv[nt][1] + bb);
        s4[2] = f2bf(accv[nt][2] + bb); s4[3] = f2bf(accv[nt][3] + bb);
        *(bf16x4*)&Vtout[((size_t)nb * DIM + nt * 16 + c) * SEQ + n0 + g * 4] = s4;
    }
}

// ---------------------------------------------------------------------------
// Flash attention: R11 structure; P-pack via v_cvt_pk_bf16_f32 (8 instrs).
// 4 waves x 32 q-rows, KVB=32, dbuf + vmcnt(8), base-2 softmax (raw v_exp).
// ---------------------------------------------------------------------------
#define KVB 32

__global__ __launch_bounds__(256, 2) void fa2_kernel(
    const unsigned short* __restrict__ Q,   // bf16, pre-scaled (log2 domain)
    const unsigned short* __restrict__ K,
    const unsigned short* __restrict__ Vt,
    float* __restrict__ Opart,              // [nsplit][4][4096][256] f32
    float2* __restrict__ ml,                // [nsplit][4*4096]  (m in log2 domain)
    int nsplit)
{
    __shared__ __align__(16) unsigned short Klds[2][KVB * 256];
    __shared__ __align__(16) unsigned short Vlds[2][256 * KVB];

    const int t = threadIdx.x;
    const int w = t >> 6, lane = t & 63;
    const int c = lane & 15, g = lane >> 4;

    int b, sidx, qt;
    if (nsplit == 4) {
        int xcd  = blockIdx.x & 7;
        int rest = blockIdx.x >> 3;
        int combo = (xcd << 1) | (rest >> 5);
        qt   = rest & 31;
        b    = combo >> 2;
        sidx = combo & 3;
    } else {
        qt   = blockIdx.x & 31;
        b    = blockIdx.x >> 5;
        sidx = 0;
    }
    const int ts = (sidx * 128) / nsplit;
    const int te = ((sidx + 1) * 128) / nsplit;

    const int wrow = qt * 128 + w * 32;

    bf16x8 qf[2][8];
    #pragma unroll
    for (int h = 0; h < 2; ++h) {
        const unsigned short* Qrow = &Q[((size_t)b * SEQ + wrow + 16 * h + c) * DIM];
        #pragma unroll
        for (int ks = 0; ks < 8; ++ks)
            qf[h][ks] = *(const bf16x8*)&Qrow[ks * 32 + g * 8];
    }

    f32x4 o[2][16];
    #pragma unroll
    for (int h = 0; h < 2; ++h)
        #pragma unroll
        for (int nt = 0; nt < 16; ++nt) o[h][nt] = f32x4{0.f, 0.f, 0.f, 0.f};
    float m[2]     = {-1e30f, -1e30f};
    float llane[2] = {0.f, 0.f};

    const char* Kb_ = (const char*)&K[(size_t)b * SEQ * DIM];
    const char* Vb_ = (const char*)&Vt[(size_t)b * DIM * SEQ];

    const int l31 = lane & 31;
    int koff[4], voff[4], dstb[4];
    const int vsw = ((lane >> 2) & 3) ^ ((lane >> 4) & 3);
    const int vcb = ((lane & 3) ^ vsw) << 4;
    #pragma unroll
    for (int ii = 0; ii < 4; ++ii) {
        int kr = 8 * w + 2 * ii + (lane >> 5);
        int sc = (kr & 3) | ((kr & 8) >> 1);              // sigma_c
        koff[ii] = kr * 512 + ((l31 ^ sc) << 4);
        int vr = 64 * w + 16 * ii + (lane >> 2);
        voff[ii] = vr * (SEQ * 2) + vcb;
        dstb[ii] = (4 * w + ii) * 1024;
    }

    #define STAGE(kt_, buf_) do {                                              \
        const size_t kb_ = (size_t)(kt_) * (KVB * DIM * 2);                    \
        const size_t vb_ = (size_t)(kt_) * (KVB * 2);                          \
        _Pragma("unroll")                                                      \
        for (int ii = 0; ii < 4; ++ii) {                                       \
            gload_lds16(Kb_ + kb_ + koff[ii], (char*)&Klds[buf_][0] + dstb[ii]); \
            gload_lds16(Vb_ + vb_ + voff[ii], (char*)&Vlds[buf_][0] + dstb[ii]); \
        }                                                                      \
    } while (0)

    STAGE(ts, 0);
    int buf = 0;

    const int xk   = (c & 7) << 3;
    const int rphi = ((c & 3) + 8 * (c >> 2));
    const int vcol = (g * 8) ^ ((((c & 3) ^ ((c >> 2) & 3))) << 3);

    for (int kt = ts; kt < te; ++kt) {
        __builtin_amdgcn_s_barrier();   // all waves done reading buf^1
        if (kt + 1 < te) {
            STAGE(kt + 1, buf ^ 1);
            asm volatile("s_waitcnt vmcnt(8)" ::: "memory");  // tile kt landed
        } else {
            asm volatile("s_waitcnt vmcnt(0)" ::: "memory");
        }
        __builtin_amdgcn_s_barrier();   // tile kt visible to all waves

        const unsigned short* Kl = &Klds[buf][0];
        const unsigned short* Vl = &Vlds[buf][0];

        f32x4 s[2][2];
        #pragma unroll
        for (int h = 0; h < 2; ++h) {
            s[h][0] = f32x4{0.f, 0.f, 0.f, 0.f};
            s[h][1] = f32x4{0.f, 0.f, 0.f, 0.f};
        }
        __builtin_amdgcn_s_setprio(1);
        #pragma unroll
        for (int ks = 0; ks < 8; ++ks) {
            int off = (ks * 32 + g * 8) ^ xk;
            bf16x8 kf0 = *(const bf16x8*)&Kl[rphi * 256 + off];
            bf16x8 kf1 = *(const bf16x8*)&Kl[(rphi + 4) * 256 + off];
            s[0][0] = __builtin_amdgcn_mfma_f32_16x16x32_bf16(kf0, qf[0][ks], s[0][0], 0, 0, 0);
            s[1][0] = __builtin_amdgcn_mfma_f32_16x16x32_bf16(kf0, qf[1][ks], s[1][0], 0, 0, 0);
            s[0][1] = __builtin_amdgcn_mfma_f32_16x16x32_bf16(kf1, qf[0][ks], s[0][1], 0, 0, 0);
            s[1][1] = __builtin_amdgcn_mfma_f32_16x16x32_bf16(kf1, qf[1][ks], s[1][1], 0, 0, 0);
        }
        __builtin_amdgcn_s_setprio(0);

        // defer-max softmax in log2 domain (threshold 11 bits ~ 8 nats)
        float pm[2];
        #pragma unroll
        for (int h = 0; h < 2; ++h)
            pm[h] = fmaxf(fmaxf(fmaxf(s[h][0][0], s[h][0][1]), fmaxf(s[h][0][2], s[h][0][3])),
                          fmaxf(fmaxf(s[h][1][0], s[h][1][1]), fmaxf(s[h][1][2], s[h][1][3])));
        bool ok = (pm[0] <= m[0] + 11.f) && (pm[1] <= m[1] + 11.f);
        if (!__all(ok)) {
            #pragma unroll
            for (int h = 0; h < 2; ++h) {
                float pr = pm[h];
                pr = fmaxf(pr, __shfl_xor(pr, 16));
                pr = fmaxf(pr, __shfl_xor(pr, 32));
                float mn = fmaxf(m[h], pr);
                float r  = EXP2(m[h] - mn);
                m[h] = mn; llane[h] *= r;
                float r0 = __shfl(r, g * 4 + 0), r1 = __shfl(r, g * 4 + 1);
                float r2 = __shfl(r, g * 4 + 2), r3 = __shfl(r, g * 4 + 3);
                #pragma unroll
                for (int nt = 0; nt < 16; ++nt) {
                    o[h][nt][0] *= r0; o[h][nt][1] *= r1;
                    o[h][nt][2] *= r2; o[h][nt][3] *= r3;
                }
            }
        }
        bf16x8 pa0, pa1;
        {
            float p0 = EXP2(s[0][0][0] - m[0]), p1 = EXP2(s[0][0][1] - m[0]);
            float p2 = EXP2(s[0][0][2] - m[0]), p3 = EXP2(s[0][0][3] - m[0]);
            float p4 = EXP2(s[0][1][0] - m[0]), p5 = EXP2(s[0][1][1] - m[0]);
            float p6 = EXP2(s[0][1][2] - m[0]), p7 = EXP2(s[0][1][3] - m[0]);
            llane[0] += ((p0 + p1) + (p2 + p3)) + ((p4 + p5) + (p6 + p7));
            union { int d[4]; bf16x8 v; } u;
            u.d[0] = cvtpk(p0, p1); u.d[1] = cvtpk(p2, p3);
            u.d[2] = cvtpk(p4, p5); u.d[3] = cvtpk(p6, p7);
            pa0 = u.v;
        }
        {
            float p0 = EXP2(s[1][0][0] - m[1]), p1 = EXP2(s[1][0][1] - m[1]);
            float p2 = EXP2(s[1][0][2] - m[1]), p3 = EXP2(s[1][0][3] - m[1]);
            float p4 = EXP2(s[1][1][0] - m[1]), p5 = EXP2(s[1][1][1] - m[1]);
            float p6 = EXP2(s[1][1][2] - m[1]), p7 = EXP2(s[1][1][3] - m[1]);
            llane[1] += ((p0 + p1) + (p2 + p3)) + ((p4 + p5) + (p6 + p7));
            union { int d[4]; bf16x8 v; } u;
            u.d[0] = cvtpk(p0, p1); u.d[1] = cvtpk(p2, p3);
            u.d[2] = cvtpk(p4, p5); u.d[3] = cvtpk(p6, p7);
            pa1 = u.v;
        }

        __builtin_amdgcn_s_setprio(1);
        #pragma unroll
        for (int nt = 0; nt < 16; ++nt) {
            bf16x8 vf = *(const bf16x8*)&Vl[(nt * 16 + c) * 32 + vcol];
            o[0][nt] = __builtin_amdgcn_mfma_f32_16x16x32_bf16(pa0, vf, o[0][nt], 0, 0, 0);
            o[1][nt] = __builtin_amdgcn_mfma_f32_16x16x32_bf16(pa1, vf, o[1][nt], 0, 0, 0);
        }
        __builtin_amdgcn_s_setprio(0);
        buf ^= 1;
    }

    #pragma unroll
    for (int h = 0; h < 2; ++h) {
        float lsum = llane[h];
        lsum += __shfl_xor(lsum, 16);
        lsum += __shfl_xor(lsum, 32);
        float inv = 1.0f / lsum;
        float i0 = __shfl(inv, g * 4 + 0), i1 = __shfl(inv, g * 4 + 1);
        float i2 = __shfl(inv, g * 4 + 2), i3 = __shfl(inv, g * 4 + 3);

        const size_t obase = ((size_t)sidx * BATCH * SEQ + (size_t)b * SEQ + wrow + 16 * h) * DIM;
        for (int nt = 0; nt < 16; ++nt) {
            Opart[obase + (size_t)(g * 4 + 0) * DIM + nt * 16 + c] = o[h][nt][0] * i0;
            Opart[obase + (size_t)(g * 4 + 1) * DIM + nt * 16 + c] = o[h][nt][1] * i1;
            Opart[obase + (size_t)(g * 4 + 2) * DIM + nt * 16 + c] = o[h][nt][2] * i2;
            Opart[obase + (size_t)(g * 4 + 3) * DIM + nt * 16 + c] = o[h][nt][3] * i3;
        }
        if (g == 0) {
            ml[(size_t)sidx * BATCH * SEQ + (size_t)b * SEQ + wrow + 16 * h + c] =
                make_float2(m[h], lsum);
        }
    }
}

// ---------------------------------------------------------------------------
// Combine 4 KV-split partials (log2-domain m): w_s = l_s * 2^(m_s - M)
// ---------------------------------------------------------------------------
__global__ __launch_bounds__(256) void combine_kernel(
    const float* __restrict__ Opart, const float2* __restrict__ ml,
    float* __restrict__ out)
{
    const int t = threadIdx.x;
    const size_t row = (size_t)blockIdx.x * 4 + (t >> 6);
    const int lane = t & 63;

    float2 e[4];
    float M = -1e30f;
    for (int s = 0; s < 4; ++s) {
        e[s] = ml[(size_t)s * BATCH * SEQ + row];
        M = fmaxf(M, e[s].x);
    }
    float wgt[4], L = 0.f;
    for (int s = 0; s < 4; ++s) { wgt[s] = e[s].y * EXP2(e[s].x - M); L += wgt[s]; }
    float invL = 1.0f / L;

    f32x4 acc = f32x4{0.f, 0.f, 0.f, 0.f};
    for (int s = 0; s < 4; ++s) {
        f32x4 v = *(const f32x4*)&Opart[((size_t)s * BATCH * SEQ + row) * DIM + lane * 4];
        float ws = wgt[s] * invL;
        acc[0] += ws * v[0]; acc[1] += ws * v[1];
        acc[2] += ws * v[2]; acc[3] += ws * v[3];
    }
    *(f32x4*)&out[row * DIM + lane * 4] = acc;
}

// ---------------------------------------------------------------------------
extern "C" void kernel_launch(void* const* d_in, const int* in_sizes, int n_in,
                              void* d_out, int out_size, void* d_ws, size_t ws_size,
                              hipStream_t stream) {
    const float* x  = (const float*)d_in[0];
    const float* z  = (const float*)d_in[1];
    const float* Wq = (const float*)d_in[2];
    const float* bq = (const float*)d_in[3];
    const float* Wk = (const float*)d_in[4];
    const float* bk = (const float*)d_in[5];
    const float* Wv = (const float*)d_in[6];
    const float* bv = (const float*)d_in[7];
    float* out = (float*)d_out;

    const size_t TENS = (size_t)BATCH * SEQ * DIM;
    unsigned short* Qb  = (unsigned short*)d_ws;
    unsigned short* Kb  = Qb + TENS;
    unsigned short* Vtb = Kb + TENS;

    const size_t base_bytes = 3 * TENS * sizeof(unsigned short);       // 24 MB
    const size_t need4 = base_bytes + 4 * TENS * sizeof(float)         // 64 MB
                       + 4 * (size_t)BATCH * SEQ * sizeof(float2);
    const int nsplit = (ws_size >= need4) ? 4 : 1;

    const float qscale = 0.0625f * LOG2E;  // 1/sqrt(D) * log2(e): base-2 softmax

    proj_kernel<false><<<256, 256, 0, stream>>>(x, Wq, bq, Qb, qscale);
    kv_proj_kernel<<<256, 256, 0, stream>>>(z, Wk, bk, Wv, bv, Kb, Vtb);

    if (nsplit == 4) {
        float*  Op  = (float*)((char*)d_ws + base_bytes);
        float2* mlb = (float2*)((char*)d_ws + base_bytes + 4 * TENS * sizeof(float));
        fa2_kernel<<<512, 256, 0, stream>>>(Qb, Kb, Vtb, Op, mlb, 4);
        combine_kernel<<<4096, 256, 0, stream>>>(Op, mlb, out);
    } else {
        float2* mlb = (float2*)((char*)d_ws + base_bytes);
        fa2_kernel<<<128, 256, 0, stream>>>(Qb, Kb, Vtb, out, mlb, 1);
    }
}

// Round 13
// 127.622 us; speedup vs baseline: 1.2483x; 1.0508x over previous
//
#include <hip/hip_runtime.h>
#include <hip/hip_bf16.h>
#include <math.h>

#define BATCH 4
#define SEQ   4096
#define DIM   256
#define AS1 __attribute__((address_space(1)))
#define AS3 __attribute__((address_space(3)))

typedef __attribute__((ext_vector_type(8))) short  bf16x8;
typedef __attribute__((ext_vector_type(4))) short  bf16x4;
typedef __attribute__((ext_vector_type(4))) float  f32x4;
typedef __attribute__((ext_vector_type(4))) int    i32x4;

#define LOG2E 1.44269504088896340736f
#define EXP2(x) __builtin_amdgcn_exp2f(x)   // raw v_exp_f32 (2^x), 1 instr

__device__ __forceinline__ short f2bf(float f) {
    union { float f; unsigned u; } v; v.f = f;
    unsigned r = (v.u + 0x7fffu + ((v.u >> 16) & 1u)) >> 16;
    return (short)r;
}

// pack two f32 -> one dword of 2 bf16 (RTNE), single instruction
__device__ __forceinline__ int cvtpk(float lo, float hi) {
    int r;
    asm("v_cvt_pk_bf16_f32 %0, %1, %2" : "=v"(r) : "v"(lo), "v"(hi));
    return r;
}

__device__ __forceinline__ void gload_lds16(const void* g, void* l) {
    __builtin_amdgcn_global_load_lds((const AS1 void*)g, (AS3 void*)l, 16, 0, 0);
}

// ---------------------------------------------------------------------------
// Projection (single): out[n][e] = (sum_d A[n][d]*W[e][d] + bias[e]) * scale
// ---------------------------------------------------------------------------
template<bool TRANS>
__global__ __launch_bounds__(256) void proj_kernel(
    const float* __restrict__ A,
    const float* __restrict__ W,
    const float* __restrict__ bias,
    unsigned short* __restrict__ out,
    float scale)
{
    __shared__ __align__(16) short Wlds[256 * 40];

    const int t    = threadIdx.x;
    const int wave = t >> 6, lane = t & 63;
    const int c    = lane & 15, g = lane >> 4;
    const int wrow = blockIdx.x * 64 + wave * 16;

    f32x4 acc[16];
    for (int nt = 0; nt < 16; ++nt) acc[nt] = f32x4{0.f, 0.f, 0.f, 0.f};

    f32x4 wpf[8];
    for (int i = 0; i < 8; ++i) {
        int f = i * 1024 + t * 4;
        wpf[i] = *(const f32x4*)&W[(f >> 5) * 256 + (f & 31)];
    }
    f32x4 a0 = *(const f32x4*)&A[(wrow + c) * 256 + g * 8];
    f32x4 a1 = *(const f32x4*)&A[(wrow + c) * 256 + g * 8 + 4];

    for (int ks = 0; ks < 8; ++ks) {
        __syncthreads();
        for (int i = 0; i < 8; ++i) {
            int f = i * 1024 + t * 4;
            bf16x4 s4;
            s4[0] = f2bf(wpf[i][0]); s4[1] = f2bf(wpf[i][1]);
            s4[2] = f2bf(wpf[i][2]); s4[3] = f2bf(wpf[i][3]);
            *(bf16x4*)&Wlds[(f >> 5) * 40 + (f & 31)] = s4;
        }
        __syncthreads();
        bf16x8 af;
        af[0] = f2bf(a0[0]); af[1] = f2bf(a0[1]); af[2] = f2bf(a0[2]); af[3] = f2bf(a0[3]);
        af[4] = f2bf(a1[0]); af[5] = f2bf(a1[1]); af[6] = f2bf(a1[2]); af[7] = f2bf(a1[3]);
        if (ks < 7) {
            for (int i = 0; i < 8; ++i) {
                int f = i * 1024 + t * 4;
                wpf[i] = *(const f32x4*)&W[(f >> 5) * 256 + (ks + 1) * 32 + (f & 31)];
            }
            a0 = *(const f32x4*)&A[(wrow + c) * 256 + (ks + 1) * 32 + g * 8];
            a1 = *(const f32x4*)&A[(wrow + c) * 256 + (ks + 1) * 32 + g * 8 + 4];
        }
        __builtin_amdgcn_s_setprio(1);
        for (int nt = 0; nt < 16; ++nt) {
            bf16x8 bfr = *(const bf16x8*)&Wlds[(nt * 16 + c) * 40 + g * 8];
            acc[nt] = __builtin_amdgcn_mfma_f32_16x16x32_bf16(af, bfr, acc[nt], 0, 0, 0);
        }
        __builtin_amdgcn_s_setprio(0);
    }

    if constexpr (TRANS) {
        const int nb = wrow >> 12, n0 = wrow & 4095;
        for (int nt = 0; nt < 16; ++nt) {
            float bv = bias[nt * 16 + c];
            bf16x4 s4;
            s4[0] = f2bf((acc[nt][0] + bv) * scale); s4[1] = f2bf((acc[nt][1] + bv) * scale);
            s4[2] = f2bf((acc[nt][2] + bv) * scale); s4[3] = f2bf((acc[nt][3] + bv) * scale);
            *(bf16x4*)&out[((size_t)nb * DIM + nt * 16 + c) * SEQ + n0 + g * 4] = s4;
        }
    } else {
        for (int nt = 0; nt < 16; ++nt) {
            float bv = bias[nt * 16 + c];
            for (int j = 0; j < 4; ++j)
                out[(size_t)(wrow + g * 4 + j) * 256 + nt * 16 + c] =
                    (unsigned short)f2bf((acc[nt][j] + bv) * scale);
        }
    }
}

// ---------------------------------------------------------------------------
// Fused K+V projection: reads z once, produces K (row-major) and Vt (trans).
// ---------------------------------------------------------------------------
__global__ __launch_bounds__(256) void kv_proj_kernel(
    const float* __restrict__ A,     // z [16384][256]
    const float* __restrict__ Wk, const float* __restrict__ bk,
    const float* __restrict__ Wv, const float* __restrict__ bv,
    unsigned short* __restrict__ Kout,   // [4][4096][256]
    unsigned short* __restrict__ Vtout)  // [4][256][4096]
{
    __shared__ __align__(16) short WldsK[256 * 40];
    __shared__ __align__(16) short WldsV[256 * 40];

    const int t    = threadIdx.x;
    const int wave = t >> 6, lane = t & 63;
    const int c    = lane & 15, g = lane >> 4;
    const int wrow = blockIdx.x * 64 + wave * 16;

    f32x4 acck[16], accv[16];
    for (int nt = 0; nt < 16; ++nt) {
        acck[nt] = f32x4{0.f, 0.f, 0.f, 0.f};
        accv[nt] = f32x4{0.f, 0.f, 0.f, 0.f};
    }

    f32x4 wpfk[8], wpfv[8];
    for (int i = 0; i < 8; ++i) {
        int f = i * 1024 + t * 4;
        wpfk[i] = *(const f32x4*)&Wk[(f >> 5) * 256 + (f & 31)];
        wpfv[i] = *(const f32x4*)&Wv[(f >> 5) * 256 + (f & 31)];
    }
    f32x4 a0 = *(const f32x4*)&A[(wrow + c) * 256 + g * 8];
    f32x4 a1 = *(const f32x4*)&A[(wrow + c) * 256 + g * 8 + 4];

    for (int ks = 0; ks < 8; ++ks) {
        __syncthreads();
        for (int i = 0; i < 8; ++i) {
            int f = i * 1024 + t * 4;
            bf16x4 sk, sv;
            sk[0] = f2bf(wpfk[i][0]); sk[1] = f2bf(wpfk[i][1]);
            sk[2] = f2bf(wpfk[i][2]); sk[3] = f2bf(wpfk[i][3]);
            sv[0] = f2bf(wpfv[i][0]); sv[1] = f2bf(wpfv[i][1]);
            sv[2] = f2bf(wpfv[i][2]); sv[3] = f2bf(wpfv[i][3]);
            *(bf16x4*)&WldsK[(f >> 5) * 40 + (f & 31)] = sk;
            *(bf16x4*)&WldsV[(f >> 5) * 40 + (f & 31)] = sv;
        }
        __syncthreads();
        bf16x8 af;
        af[0] = f2bf(a0[0]); af[1] = f2bf(a0[1]); af[2] = f2bf(a0[2]); af[3] = f2bf(a0[3]);
        af[4] = f2bf(a1[0]); af[5] = f2bf(a1[1]); af[6] = f2bf(a1[2]); af[7] = f2bf(a1[3]);
        if (ks < 7) {
            for (int i = 0; i < 8; ++i) {
                int f = i * 1024 + t * 4;
                wpfk[i] = *(const f32x4*)&Wk[(f >> 5) * 256 + (ks + 1) * 32 + (f & 31)];
                wpfv[i] = *(const f32x4*)&Wv[(f >> 5) * 256 + (ks + 1) * 32 + (f & 31)];
            }
            a0 = *(const f32x4*)&A[(wrow + c) * 256 + (ks + 1) * 32 + g * 8];
            a1 = *(const f32x4*)&A[(wrow + c) * 256 + (ks + 1) * 32 + g * 8 + 4];
        }
        __builtin_amdgcn_s_setprio(1);
        for (int nt = 0; nt < 16; ++nt) {
            bf16x8 bk_ = *(const bf16x8*)&WldsK[(nt * 16 + c) * 40 + g * 8];
            acck[nt] = __builtin_amdgcn_mfma_f32_16x16x32_bf16(af, bk_, acck[nt], 0, 0, 0);
            bf16x8 bv_ = *(const bf16x8*)&WldsV[(nt * 16 + c) * 40 + g * 8];
            accv[nt] = __builtin_amdgcn_mfma_f32_16x16x32_bf16(af, bv_, accv[nt], 0, 0, 0);
        }
        __builtin_amdgcn_s_setprio(0);
    }

    // K: row-major
    for (int nt = 0; nt < 16; ++nt) {
        float bb = bk[nt * 16 + c];
        for (int j = 0; j < 4; ++j)
            Kout[(size_t)(wrow + g * 4 + j) * 256 + nt * 16 + c] =
                (unsigned short)f2bf(acck[nt][j] + bb);
    }
    // V: transposed per batch
    const int nb = wrow >> 12, n0 = wrow & 4095;
    for (int nt = 0; nt < 16; ++nt) {
        float bb = bv[nt * 16 + c];
        bf16x4 s4;
        s4[0] = f2bf(accv[nt][0] + bb); s4[1] = f2bf(accv[nt][1] + bb);
        s4[2] = f2bf(accv[nt][2] + bb); s4[3] = f2bf(accv[nt][3] + bb);
        *(bf16x4*)&Vtout[((size_t)nb * DIM + nt * 16 + c) * SEQ + n0 + g * 4] = s4;
    }
}

// ---------------------------------------------------------------------------
// Flash attention: single barrier/tile, bf16 partials.
// 4 waves x 32 q-rows, KVB=32, dbuf, base-2 softmax (raw v_exp), cvt_pk P.
// ---------------------------------------------------------------------------
#define KVB 32

__global__ __launch_bounds__(256, 2) void fa2_kernel(
    const unsigned short* __restrict__ Q,   // bf16, pre-scaled (log2 domain)
    const unsigned short* __restrict__ K,
    const unsigned short* __restrict__ Vt,
    unsigned short* __restrict__ Opart,     // [nsplit][4][4096][256] bf16 (l-normalized)
    float2* __restrict__ ml,                // [nsplit][4*4096]  (m in log2 domain)
    int nsplit)
{
    __shared__ __align__(16) unsigned short Klds[2][KVB * 256];
    __shared__ __align__(16) unsigned short Vlds[2][256 * KVB];

    const int t = threadIdx.x;
    const int w = t >> 6, lane = t & 63;
    const int c = lane & 15, g = lane >> 4;

    int b, sidx, qt;
    if (nsplit == 4) {
        int xcd  = blockIdx.x & 7;
        int rest = blockIdx.x >> 3;
        int combo = (xcd << 1) | (rest >> 5);
        qt   = rest & 31;
        b    = combo >> 2;
        sidx = combo & 3;
    } else {
        qt   = blockIdx.x & 31;
        b    = blockIdx.x >> 5;
        sidx = 0;
    }
    const int ts = (sidx * 128) / nsplit;
    const int te = ((sidx + 1) * 128) / nsplit;

    const int wrow = qt * 128 + w * 32;

    bf16x8 qf[2][8];
    #pragma unroll
    for (int h = 0; h < 2; ++h) {
        const unsigned short* Qrow = &Q[((size_t)b * SEQ + wrow + 16 * h + c) * DIM];
        #pragma unroll
        for (int ks = 0; ks < 8; ++ks)
            qf[h][ks] = *(const bf16x8*)&Qrow[ks * 32 + g * 8];
    }

    f32x4 o[2][16];
    #pragma unroll
    for (int h = 0; h < 2; ++h)
        #pragma unroll
        for (int nt = 0; nt < 16; ++nt) o[h][nt] = f32x4{0.f, 0.f, 0.f, 0.f};
    float m[2]     = {-1e30f, -1e30f};
    float llane[2] = {0.f, 0.f};

    const char* Kb_ = (const char*)&K[(size_t)b * SEQ * DIM];
    const char* Vb_ = (const char*)&Vt[(size_t)b * DIM * SEQ];

    const int l31 = lane & 31;
    int koff[4], voff[4], dstb[4];
    const int vsw = ((lane >> 2) & 3) ^ ((lane >> 4) & 3);
    const int vcb = ((lane & 3) ^ vsw) << 4;
    #pragma unroll
    for (int ii = 0; ii < 4; ++ii) {
        int kr = 8 * w + 2 * ii + (lane >> 5);
        int sc = (kr & 3) | ((kr & 8) >> 1);              // sigma_c
        koff[ii] = kr * 512 + ((l31 ^ sc) << 4);
        int vr = 64 * w + 16 * ii + (lane >> 2);
        voff[ii] = vr * (SEQ * 2) + vcb;
        dstb[ii] = (4 * w + ii) * 1024;
    }

    #define STAGE(kt_, buf_) do {                                              \
        const size_t kb_ = (size_t)(kt_) * (KVB * DIM * 2);                    \
        const size_t vb_ = (size_t)(kt_) * (KVB * 2);                          \
        _Pragma("unroll")                                                      \
        for (int ii = 0; ii < 4; ++ii) {                                       \
            gload_lds16(Kb_ + kb_ + koff[ii], (char*)&Klds[buf_][0] + dstb[ii]); \
            gload_lds16(Vb_ + vb_ + voff[ii], (char*)&Vlds[buf_][0] + dstb[ii]); \
        }                                                                      \
    } while (0)

    STAGE(ts, 0);
    int buf = 0;

    const int xk   = (c & 7) << 3;
    const int rphi = ((c & 3) + 8 * (c >> 2));
    const int vcol = (g * 8) ^ ((((c & 3) ^ ((c >> 2) & 3))) << 3);

    for (int kt = ts; kt < te; ++kt) {
        // Single barrier per tile: own vmcnt(0) proves this wave's tile-kt
        // DMAs landed; barrier then jointly proves (a) ALL waves' kt DMAs
        // landed, (b) all waves finished reading buf^1 (their compute of
        // tile kt-1 precedes the barrier). STAGE after the barrier may
        // therefore safely overwrite buf^1.
        asm volatile("s_waitcnt vmcnt(0)" ::: "memory");
        __builtin_amdgcn_s_barrier();
        if (kt + 1 < te) STAGE(kt + 1, buf ^ 1);

        const unsigned short* Kl = &Klds[buf][0];
        const unsigned short* Vl = &Vlds[buf][0];

        f32x4 s[2][2];
        #pragma unroll
        for (int h = 0; h < 2; ++h) {
            s[h][0] = f32x4{0.f, 0.f, 0.f, 0.f};
            s[h][1] = f32x4{0.f, 0.f, 0.f, 0.f};
        }
        __builtin_amdgcn_s_setprio(1);
        #pragma unroll
        for (int ks = 0; ks < 8; ++ks) {
            int off = (ks * 32 + g * 8) ^ xk;
            bf16x8 kf0 = *(const bf16x8*)&Kl[rphi * 256 + off];
            bf16x8 kf1 = *(const bf16x8*)&Kl[(rphi + 4) * 256 + off];
            s[0][0] = __builtin_amdgcn_mfma_f32_16x16x32_bf16(kf0, qf[0][ks], s[0][0], 0, 0, 0);
            s[1][0] = __builtin_amdgcn_mfma_f32_16x16x32_bf16(kf0, qf[1][ks], s[1][0], 0, 0, 0);
            s[0][1] = __builtin_amdgcn_mfma_f32_16x16x32_bf16(kf1, qf[0][ks], s[0][1], 0, 0, 0);
            s[1][1] = __builtin_amdgcn_mfma_f32_16x16x32_bf16(kf1, qf[1][ks], s[1][1], 0, 0, 0);
        }
        __builtin_amdgcn_s_setprio(0);

        // defer-max softmax in log2 domain (threshold 11 bits ~ 8 nats)
        float pm[2];
        #pragma unroll
        for (int h = 0; h < 2; ++h)
            pm[h] = fmaxf(fmaxf(fmaxf(s[h][0][0], s[h][0][1]), fmaxf(s[h][0][2], s[h][0][3])),
                          fmaxf(fmaxf(s[h][1][0], s[h][1][1]), fmaxf(s[h][1][2], s[h][1][3])));
        bool ok = (pm[0] <= m[0] + 11.f) && (pm[1] <= m[1] + 11.f);
        if (!__all(ok)) {
            #pragma unroll
            for (int h = 0; h < 2; ++h) {
                float pr = pm[h];
                pr = fmaxf(pr, __shfl_xor(pr, 16));
                pr = fmaxf(pr, __shfl_xor(pr, 32));
                float mn = fmaxf(m[h], pr);
                float r  = EXP2(m[h] - mn);
                m[h] = mn; llane[h] *= r;
                float r0 = __shfl(r, g * 4 + 0), r1 = __shfl(r, g * 4 + 1);
                float r2 = __shfl(r, g * 4 + 2), r3 = __shfl(r, g * 4 + 3);
                #pragma unroll
                for (int nt = 0; nt < 16; ++nt) {
                    o[h][nt][0] *= r0; o[h][nt][1] *= r1;
                    o[h][nt][2] *= r2; o[h][nt][3] *= r3;
                }
            }
        }
        bf16x8 pa0, pa1;
        {
            float p0 = EXP2(s[0][0][0] - m[0]), p1 = EXP2(s[0][0][1] - m[0]);
            float p2 = EXP2(s[0][0][2] - m[0]), p3 = EXP2(s[0][0][3] - m[0]);
            float p4 = EXP2(s[0][1][0] - m[0]), p5 = EXP2(s[0][1][1] - m[0]);
            float p6 = EXP2(s[0][1][2] - m[0]), p7 = EXP2(s[0][1][3] - m[0]);
            llane[0] += ((p0 + p1) + (p2 + p3)) + ((p4 + p5) + (p6 + p7));
            union { int d[4]; bf16x8 v; } u;
            u.d[0] = cvtpk(p0, p1); u.d[1] = cvtpk(p2, p3);
            u.d[2] = cvtpk(p4, p5); u.d[3] = cvtpk(p6, p7);
            pa0 = u.v;
        }
        {
            float p0 = EXP2(s[1][0][0] - m[1]), p1 = EXP2(s[1][0][1] - m[1]);
            float p2 = EXP2(s[1][0][2] - m[1]), p3 = EXP2(s[1][0][3] - m[1]);
            float p4 = EXP2(s[1][1][0] - m[1]), p5 = EXP2(s[1][1][1] - m[1]);
            float p6 = EXP2(s[1][1][2] - m[1]), p7 = EXP2(s[1][1][3] - m[1]);
            llane[1] += ((p0 + p1) + (p2 + p3)) + ((p4 + p5) + (p6 + p7));
            union { int d[4]; bf16x8 v; } u;
            u.d[0] = cvtpk(p0, p1); u.d[1] = cvtpk(p2, p3);
            u.d[2] = cvtpk(p4, p5); u.d[3] = cvtpk(p6, p7);
            pa1 = u.v;
        }

        __builtin_amdgcn_s_setprio(1);
        #pragma unroll
        for (int nt = 0; nt < 16; ++nt) {
            bf16x8 vf = *(const bf16x8*)&Vl[(nt * 16 + c) * 32 + vcol];
            o[0][nt] = __builtin_amdgcn_mfma_f32_16x16x32_bf16(pa0, vf, o[0][nt], 0, 0, 0);
            o[1][nt] = __builtin_amdgcn_mfma_f32_16x16x32_bf16(pa1, vf, o[1][nt], 0, 0, 0);
        }
        __builtin_amdgcn_s_setprio(0);
        buf ^= 1;
    }

    #pragma unroll
    for (int h = 0; h < 2; ++h) {
        float lsum = llane[h];
        lsum += __shfl_xor(lsum, 16);
        lsum += __shfl_xor(lsum, 32);
        float inv = 1.0f / lsum;
        float i0 = __shfl(inv, g * 4 + 0), i1 = __shfl(inv, g * 4 + 1);
        float i2 = __shfl(inv, g * 4 + 2), i3 = __shfl(inv, g * 4 + 3);

        const size_t obase = ((size_t)sidx * BATCH * SEQ + (size_t)b * SEQ + wrow + 16 * h) * DIM;
        for (int nt = 0; nt < 16; ++nt) {
            Opart[obase + (size_t)(g * 4 + 0) * DIM + nt * 16 + c] =
                (unsigned short)f2bf(o[h][nt][0] * i0);
            Opart[obase + (size_t)(g * 4 + 1) * DIM + nt * 16 + c] =
                (unsigned short)f2bf(o[h][nt][1] * i1);
            Opart[obase + (size_t)(g * 4 + 2) * DIM + nt * 16 + c] =
                (unsigned short)f2bf(o[h][nt][2] * i2);
            Opart[obase + (size_t)(g * 4 + 3) * DIM + nt * 16 + c] =
                (unsigned short)f2bf(o[h][nt][3] * i3);
        }
        if (g == 0) {
            ml[(size_t)sidx * BATCH * SEQ + (size_t)b * SEQ + wrow + 16 * h + c] =
                make_float2(m[h], lsum);
        }
    }
}

// ---------------------------------------------------------------------------
// Combine 4 KV-split bf16 partials (log2-domain m): w_s = l_s * 2^(m_s - M)
// ---------------------------------------------------------------------------
__global__ __launch_bounds__(256) void combine_kernel(
    const unsigned short* __restrict__ Opart, const float2* __restrict__ ml,
    float* __restrict__ out)
{
    const int t = threadIdx.x;
    const size_t row = (size_t)blockIdx.x * 4 + (t >> 6);
    const int lane = t & 63;

    float2 e[4];
    float M = -1e30f;
    for (int s = 0; s < 4; ++s) {
        e[s] = ml[(size_t)s * BATCH * SEQ + row];
        M = fmaxf(M, e[s].x);
    }
    float wgt[4], L = 0.f;
    for (int s = 0; s < 4; ++s) { wgt[s] = e[s].y * EXP2(e[s].x - M); L += wgt[s]; }
    float invL = 1.0f / L;

    f32x4 acc = f32x4{0.f, 0.f, 0.f, 0.f};
    for (int s = 0; s < 4; ++s) {
        bf16x4 v = *(const bf16x4*)&Opart[((size_t)s * BATCH * SEQ + row) * DIM + lane * 4];
        float ws = wgt[s] * invL;
        union { unsigned u; float f; } c0, c1, c2, c3;
        c0.u = ((unsigned)(unsigned short)v[0]) << 16;
        c1.u = ((unsigned)(unsigned short)v[1]) << 16;
        c2.u = ((unsigned)(unsigned short)v[2]) << 16;
        c3.u = ((unsigned)(unsigned short)v[3]) << 16;
        acc[0] += ws * c0.f; acc[1] += ws * c1.f;
        acc[2] += ws * c2.f; acc[3] += ws * c3.f;
    }
    *(f32x4*)&out[row * DIM + lane * 4] = acc;
}

// ---------------------------------------------------------------------------
extern "C" void kernel_launch(void* const* d_in, const int* in_sizes, int n_in,
                              void* d_out, int out_size, void* d_ws, size_t ws_size,
                              hipStream_t stream) {
    const float* x  = (const float*)d_in[0];
    const float* z  = (const float*)d_in[1];
    const float* Wq = (const float*)d_in[2];
    const float* bq = (const float*)d_in[3];
    const float* Wk = (const float*)d_in[4];
    const float* bk = (const float*)d_in[5];
    const float* Wv = (const float*)d_in[6];
    const float* bv = (const float*)d_in[7];
    float* out = (float*)d_out;

    const size_t TENS = (size_t)BATCH * SEQ * DIM;
    unsigned short* Qb  = (unsigned short*)d_ws;
    unsigned short* Kb  = Qb + TENS;
    unsigned short* Vtb = Kb + TENS;

    const size_t base_bytes = 3 * TENS * sizeof(unsigned short);       // 24 MB
    const size_t need4 = base_bytes + 4 * TENS * sizeof(unsigned short) // 32 MB partials
                       + 4 * (size_t)BATCH * SEQ * sizeof(float2);
    const int nsplit = (ws_size >= need4) ? 4 : 1;

    const float qscale = 0.0625f * LOG2E;  // 1/sqrt(D) * log2(e): base-2 softmax

    proj_kernel<false><<<256, 256, 0, stream>>>(x, Wq, bq, Qb, qscale);
    kv_proj_kernel<<<256, 256, 0, stream>>>(z, Wk, bk, Wv, bv, Kb, Vtb);

    if (nsplit == 4) {
        unsigned short* Op = (unsigned short*)((char*)d_ws + base_bytes);
        float2* mlb = (float2*)((char*)d_ws + base_bytes + 4 * TENS * sizeof(unsigned short));
        fa2_kernel<<<512, 256, 0, stream>>>(Qb, Kb, Vtb, Op, mlb, 4);
        combine_kernel<<<4096, 256, 0, stream>>>(Op, mlb, out);
    } else {
        // fallback: bf16 partial written to scratch, then combine-less copy is
        // not available; reuse 4-split path requirements are modest (56.5 MB),
        // so in practice nsplit==4 always holds. For safety, run single-split
        // into the same bf16 buffer and expand to f32 via combine with s==0
        // weights — here we simply run the 4-split path only when ws allows,
        // else a minimal single-split with direct f32 write is emulated by
        // using the bf16 buffer as staging and a 1-split combine.
        unsigned short* Op = (unsigned short*)((char*)d_ws + base_bytes);
        float2* mlb = (float2*)((char*)d_ws + base_bytes + TENS * sizeof(unsigned short));
        fa2_kernel<<<128, 256, 0, stream>>>(Qb, Kb, Vtb, Op, mlb, 1);
        // 1-split "combine": out = Opart (already l-normalized)
        // reuse combine with all four slots pointing at the same data would
        // quadruple-count; instead do a simple expand here:
        // (grid-stride bf16->f32 copy)
        struct Local {
            static __global__ void expand(const unsigned short* in, float* o) {
                size_t i = (size_t)blockIdx.x * blockDim.x + threadIdx.x;
                union { unsigned u; float f; } v;
                v.u = ((unsigned)in[i]) << 16;
                o[i] = v.f;
            }
        };
        hipLaunchKernelGGL(Local::expand, dim3(TENS / 256), dim3(256), 0, stream, Op, out);
    }
}

// Round 14
// 122.873 us; speedup vs baseline: 1.2965x; 1.0386x over previous
//
#include <hip/hip_runtime.h>
#include <hip/hip_bf16.h>
#include <math.h>

#define BATCH 4
#define SEQ   4096
#define DIM   256
#define AS1 __attribute__((address_space(1)))
#define AS3 __attribute__((address_space(3)))

typedef __attribute__((ext_vector_type(8))) short  bf16x8;
typedef __attribute__((ext_vector_type(4))) short  bf16x4;
typedef __attribute__((ext_vector_type(4))) float  f32x4;
typedef __attribute__((ext_vector_type(4))) int    i32x4;

#define LOG2E 1.44269504088896340736f
#define EXP2(x) __builtin_amdgcn_exp2f(x)   // raw v_exp_f32 (2^x), 1 instr

__device__ __forceinline__ short f2bf(float f) {
    union { float f; unsigned u; } v; v.f = f;
    unsigned r = (v.u + 0x7fffu + ((v.u >> 16) & 1u)) >> 16;
    return (short)r;
}

// pack two f32 -> one dword of 2 bf16 (RTNE), single instruction
__device__ __forceinline__ int cvtpk(float lo, float hi) {
    int r;
    asm("v_cvt_pk_bf16_f32 %0, %1, %2" : "=v"(r) : "v"(lo), "v"(hi));
    return r;
}

__device__ __forceinline__ void gload_lds16(const void* g, void* l) {
    __builtin_amdgcn_global_load_lds((const AS1 void*)g, (AS3 void*)l, 16, 0, 0);
}

// ---------------------------------------------------------------------------
// Projection (single): out[n][e] = (sum_d A[n][d]*W[e][d] + bias[e]) * scale
// 512 thr / 8 waves: wave w -> rows (w&3)*16, output-col half (w>>2).
// ---------------------------------------------------------------------------
template<bool TRANS>
__global__ __launch_bounds__(512) void proj_kernel(
    const float* __restrict__ A,
    const float* __restrict__ W,
    const float* __restrict__ bias,
    unsigned short* __restrict__ out,
    float scale)
{
    __shared__ __align__(16) short Wlds[256 * 40];

    const int t    = threadIdx.x;
    const int wave = t >> 6, lane = t & 63;
    const int rw   = wave & 3, nh = wave >> 2;
    const int c    = lane & 15, g = lane >> 4;
    const int wrow = blockIdx.x * 64 + rw * 16;

    f32x4 acc[8];
    for (int nt = 0; nt < 8; ++nt) acc[nt] = f32x4{0.f, 0.f, 0.f, 0.f};

    f32x4 wpf[4];
    for (int i = 0; i < 4; ++i) {
        int f = i * 2048 + t * 4;
        wpf[i] = *(const f32x4*)&W[(f >> 5) * 256 + (f & 31)];
    }
    f32x4 a0 = *(const f32x4*)&A[(wrow + c) * 256 + g * 8];
    f32x4 a1 = *(const f32x4*)&A[(wrow + c) * 256 + g * 8 + 4];

    for (int ks = 0; ks < 8; ++ks) {
        __syncthreads();
        for (int i = 0; i < 4; ++i) {
            int f = i * 2048 + t * 4;
            bf16x4 s4;
            s4[0] = f2bf(wpf[i][0]); s4[1] = f2bf(wpf[i][1]);
            s4[2] = f2bf(wpf[i][2]); s4[3] = f2bf(wpf[i][3]);
            *(bf16x4*)&Wlds[(f >> 5) * 40 + (f & 31)] = s4;
        }
        __syncthreads();
        bf16x8 af;
        af[0] = f2bf(a0[0]); af[1] = f2bf(a0[1]); af[2] = f2bf(a0[2]); af[3] = f2bf(a0[3]);
        af[4] = f2bf(a1[0]); af[5] = f2bf(a1[1]); af[6] = f2bf(a1[2]); af[7] = f2bf(a1[3]);
        if (ks < 7) {
            for (int i = 0; i < 4; ++i) {
                int f = i * 2048 + t * 4;
                wpf[i] = *(const f32x4*)&W[(f >> 5) * 256 + (ks + 1) * 32 + (f & 31)];
            }
            a0 = *(const f32x4*)&A[(wrow + c) * 256 + (ks + 1) * 32 + g * 8];
            a1 = *(const f32x4*)&A[(wrow + c) * 256 + (ks + 1) * 32 + g * 8 + 4];
        }
        __builtin_amdgcn_s_setprio(1);
        for (int nt = 0; nt < 8; ++nt) {
            int e = (nh * 8 + nt) * 16 + c;
            bf16x8 bfr = *(const bf16x8*)&Wlds[e * 40 + g * 8];
            acc[nt] = __builtin_amdgcn_mfma_f32_16x16x32_bf16(af, bfr, acc[nt], 0, 0, 0);
        }
        __builtin_amdgcn_s_setprio(0);
    }

    if constexpr (TRANS) {
        const int nb = wrow >> 12, n0 = wrow & 4095;
        for (int nt = 0; nt < 8; ++nt) {
            int e = (nh * 8 + nt) * 16 + c;
            float bv = bias[e];
            bf16x4 s4;
            s4[0] = f2bf((acc[nt][0] + bv) * scale); s4[1] = f2bf((acc[nt][1] + bv) * scale);
            s4[2] = f2bf((acc[nt][2] + bv) * scale); s4[3] = f2bf((acc[nt][3] + bv) * scale);
            *(bf16x4*)&out[((size_t)nb * DIM + e) * SEQ + n0 + g * 4] = s4;
        }
    } else {
        for (int nt = 0; nt < 8; ++nt) {
            int e = (nh * 8 + nt) * 16 + c;
            float bv = bias[e];
            for (int j = 0; j < 4; ++j)
                out[(size_t)(wrow + g * 4 + j) * 256 + e] =
                    (unsigned short)f2bf((acc[nt][j] + bv) * scale);
        }
    }
}

// ---------------------------------------------------------------------------
// Fused K+V projection, 512 thr / 8 waves (same decomposition as proj).
// ---------------------------------------------------------------------------
__global__ __launch_bounds__(512) void kv_proj_kernel(
    const float* __restrict__ A,     // z [16384][256]
    const float* __restrict__ Wk, const float* __restrict__ bk,
    const float* __restrict__ Wv, const float* __restrict__ bv,
    unsigned short* __restrict__ Kout,   // [4][4096][256]
    unsigned short* __restrict__ Vtout)  // [4][256][4096]
{
    __shared__ __align__(16) short WldsK[256 * 40];
    __shared__ __align__(16) short WldsV[256 * 40];

    const int t    = threadIdx.x;
    const int wave = t >> 6, lane = t & 63;
    const int rw   = wave & 3, nh = wave >> 2;
    const int c    = lane & 15, g = lane >> 4;
    const int wrow = blockIdx.x * 64 + rw * 16;

    f32x4 acck[8], accv[8];
    for (int nt = 0; nt < 8; ++nt) {
        acck[nt] = f32x4{0.f, 0.f, 0.f, 0.f};
        accv[nt] = f32x4{0.f, 0.f, 0.f, 0.f};
    }

    f32x4 wpfk[4], wpfv[4];
    for (int i = 0; i < 4; ++i) {
        int f = i * 2048 + t * 4;
        wpfk[i] = *(const f32x4*)&Wk[(f >> 5) * 256 + (f & 31)];
        wpfv[i] = *(const f32x4*)&Wv[(f >> 5) * 256 + (f & 31)];
    }
    f32x4 a0 = *(const f32x4*)&A[(wrow + c) * 256 + g * 8];
    f32x4 a1 = *(const f32x4*)&A[(wrow + c) * 256 + g * 8 + 4];

    for (int ks = 0; ks < 8; ++ks) {
        __syncthreads();
        for (int i = 0; i < 4; ++i) {
            int f = i * 2048 + t * 4;
            bf16x4 sk, sv;
            sk[0] = f2bf(wpfk[i][0]); sk[1] = f2bf(wpfk[i][1]);
            sk[2] = f2bf(wpfk[i][2]); sk[3] = f2bf(wpfk[i][3]);
            sv[0] = f2bf(wpfv[i][0]); sv[1] = f2bf(wpfv[i][1]);
            sv[2] = f2bf(wpfv[i][2]); sv[3] = f2bf(wpfv[i][3]);
            *(bf16x4*)&WldsK[(f >> 5) * 40 + (f & 31)] = sk;
            *(bf16x4*)&WldsV[(f >> 5) * 40 + (f & 31)] = sv;
        }
        __syncthreads();
        bf16x8 af;
        af[0] = f2bf(a0[0]); af[1] = f2bf(a0[1]); af[2] = f2bf(a0[2]); af[3] = f2bf(a0[3]);
        af[4] = f2bf(a1[0]); af[5] = f2bf(a1[1]); af[6] = f2bf(a1[2]); af[7] = f2bf(a1[3]);
        if (ks < 7) {
            for (int i = 0; i < 4; ++i) {
                int f = i * 2048 + t * 4;
                wpfk[i] = *(const f32x4*)&Wk[(f >> 5) * 256 + (ks + 1) * 32 + (f & 31)];
                wpfv[i] = *(const f32x4*)&Wv[(f >> 5) * 256 + (ks + 1) * 32 + (f & 31)];
            }
            a0 = *(const f32x4*)&A[(wrow + c) * 256 + (ks + 1) * 32 + g * 8];
            a1 = *(const f32x4*)&A[(wrow + c) * 256 + (ks + 1) * 32 + g * 8 + 4];
        }
        __builtin_amdgcn_s_setprio(1);
        for (int nt = 0; nt < 8; ++nt) {
            int e = (nh * 8 + nt) * 16 + c;
            bf16x8 bk_ = *(const bf16x8*)&WldsK[e * 40 + g * 8];
            acck[nt] = __builtin_amdgcn_mfma_f32_16x16x32_bf16(af, bk_, acck[nt], 0, 0, 0);
            bf16x8 bv_ = *(const bf16x8*)&WldsV[e * 40 + g * 8];
            accv[nt] = __builtin_amdgcn_mfma_f32_16x16x32_bf16(af, bv_, accv[nt], 0, 0, 0);
        }
        __builtin_amdgcn_s_setprio(0);
    }

    // K: row-major
    for (int nt = 0; nt < 8; ++nt) {
        int e = (nh * 8 + nt) * 16 + c;
        float bb = bk[e];
        for (int j = 0; j < 4; ++j)
            Kout[(size_t)(wrow + g * 4 + j) * 256 + e] =
                (unsigned short)f2bf(acck[nt][j] + bb);
    }
    // V: transposed per batch
    const int nb = wrow >> 12, n0 = wrow & 4095;
    for (int nt = 0; nt < 8; ++nt) {
        int e = (nh * 8 + nt) * 16 + c;
        float bb = bv[e];
        bf16x4 s4;
        s4[0] = f2bf(accv[nt][0] + bb); s4[1] = f2bf(accv[nt][1] + bb);
        s4[2] = f2bf(accv[nt][2] + bb); s4[3] = f2bf(accv[nt][3] + bb);
        *(bf16x4*)&Vtout[((size_t)nb * DIM + e) * SEQ + n0 + g * 4] = s4;
    }
}

// ---------------------------------------------------------------------------
// Flash attention: single barrier/tile, bf16 partials.
// 4 waves x 32 q-rows, KVB=32, dbuf, base-2 softmax (raw v_exp), cvt_pk P.
// ---------------------------------------------------------------------------
#define KVB 32

__global__ __launch_bounds__(256, 2) void fa2_kernel(
    const unsigned short* __restrict__ Q,   // bf16, pre-scaled (log2 domain)
    const unsigned short* __restrict__ K,
    const unsigned short* __restrict__ Vt,
    unsigned short* __restrict__ Opart,     // [nsplit][4][4096][256] bf16 (l-normalized)
    float2* __restrict__ ml,                // [nsplit][4*4096]  (m in log2 domain)
    int nsplit)
{
    __shared__ __align__(16) unsigned short Klds[2][KVB * 256];
    __shared__ __align__(16) unsigned short Vlds[2][256 * KVB];

    const int t = threadIdx.x;
    const int w = t >> 6, lane = t & 63;
    const int c = lane & 15, g = lane >> 4;

    int b, sidx, qt;
    if (nsplit == 4) {
        int xcd  = blockIdx.x & 7;
        int rest = blockIdx.x >> 3;
        int combo = (xcd << 1) | (rest >> 5);
        qt   = rest & 31;
        b    = combo >> 2;
        sidx = combo & 3;
    } else {
        qt   = blockIdx.x & 31;
        b    = blockIdx.x >> 5;
        sidx = 0;
    }
    const int ts = (sidx * 128) / nsplit;
    const int te = ((sidx + 1) * 128) / nsplit;

    const int wrow = qt * 128 + w * 32;

    bf16x8 qf[2][8];
    #pragma unroll
    for (int h = 0; h < 2; ++h) {
        const unsigned short* Qrow = &Q[((size_t)b * SEQ + wrow + 16 * h + c) * DIM];
        #pragma unroll
        for (int ks = 0; ks < 8; ++ks)
            qf[h][ks] = *(const bf16x8*)&Qrow[ks * 32 + g * 8];
    }

    f32x4 o[2][16];
    #pragma unroll
    for (int h = 0; h < 2; ++h)
        #pragma unroll
        for (int nt = 0; nt < 16; ++nt) o[h][nt] = f32x4{0.f, 0.f, 0.f, 0.f};
    float m[2]     = {-1e30f, -1e30f};
    float llane[2] = {0.f, 0.f};

    const char* Kb_ = (const char*)&K[(size_t)b * SEQ * DIM];
    const char* Vb_ = (const char*)&Vt[(size_t)b * DIM * SEQ];

    const int l31 = lane & 31;
    int koff[4], voff[4], dstb[4];
    const int vsw = ((lane >> 2) & 3) ^ ((lane >> 4) & 3);
    const int vcb = ((lane & 3) ^ vsw) << 4;
    #pragma unroll
    for (int ii = 0; ii < 4; ++ii) {
        int kr = 8 * w + 2 * ii + (lane >> 5);
        int sc = (kr & 3) | ((kr & 8) >> 1);              // sigma_c
        koff[ii] = kr * 512 + ((l31 ^ sc) << 4);
        int vr = 64 * w + 16 * ii + (lane >> 2);
        voff[ii] = vr * (SEQ * 2) + vcb;
        dstb[ii] = (4 * w + ii) * 1024;
    }

    #define STAGE(kt_, buf_) do {                                              \
        const size_t kb_ = (size_t)(kt_) * (KVB * DIM * 2);                    \
        const size_t vb_ = (size_t)(kt_) * (KVB * 2);                          \
        _Pragma("unroll")                                                      \
        for (int ii = 0; ii < 4; ++ii) {                                       \
            gload_lds16(Kb_ + kb_ + koff[ii], (char*)&Klds[buf_][0] + dstb[ii]); \
            gload_lds16(Vb_ + vb_ + voff[ii], (char*)&Vlds[buf_][0] + dstb[ii]); \
        }                                                                      \
    } while (0)

    STAGE(ts, 0);
    int buf = 0;

    const int xk   = (c & 7) << 3;
    const int rphi = ((c & 3) + 8 * (c >> 2));
    const int vcol = (g * 8) ^ ((((c & 3) ^ ((c >> 2) & 3))) << 3);

    for (int kt = ts; kt < te; ++kt) {
        // Single barrier per tile: own vmcnt(0) proves this wave's tile-kt
        // DMAs landed; barrier then jointly proves (a) ALL waves' kt DMAs
        // landed, (b) all waves finished reading buf^1.
        asm volatile("s_waitcnt vmcnt(0)" ::: "memory");
        __builtin_amdgcn_s_barrier();
        if (kt + 1 < te) STAGE(kt + 1, buf ^ 1);

        const unsigned short* Kl = &Klds[buf][0];
        const unsigned short* Vl = &Vlds[buf][0];

        f32x4 s[2][2];
        #pragma unroll
        for (int h = 0; h < 2; ++h) {
            s[h][0] = f32x4{0.f, 0.f, 0.f, 0.f};
            s[h][1] = f32x4{0.f, 0.f, 0.f, 0.f};
        }
        __builtin_amdgcn_s_setprio(1);
        #pragma unroll
        for (int ks = 0; ks < 8; ++ks) {
            int off = (ks * 32 + g * 8) ^ xk;
            bf16x8 kf0 = *(const bf16x8*)&Kl[rphi * 256 + off];
            bf16x8 kf1 = *(const bf16x8*)&Kl[(rphi + 4) * 256 + off];
            s[0][0] = __builtin_amdgcn_mfma_f32_16x16x32_bf16(kf0, qf[0][ks], s[0][0], 0, 0, 0);
            s[1][0] = __builtin_amdgcn_mfma_f32_16x16x32_bf16(kf0, qf[1][ks], s[1][0], 0, 0, 0);
            s[0][1] = __builtin_amdgcn_mfma_f32_16x16x32_bf16(kf1, qf[0][ks], s[0][1], 0, 0, 0);
            s[1][1] = __builtin_amdgcn_mfma_f32_16x16x32_bf16(kf1, qf[1][ks], s[1][1], 0, 0, 0);
        }
        __builtin_amdgcn_s_setprio(0);

        // defer-max softmax in log2 domain (threshold 11 bits ~ 8 nats)
        float pm[2];
        #pragma unroll
        for (int h = 0; h < 2; ++h)
            pm[h] = fmaxf(fmaxf(fmaxf(s[h][0][0], s[h][0][1]), fmaxf(s[h][0][2], s[h][0][3])),
                          fmaxf(fmaxf(s[h][1][0], s[h][1][1]), fmaxf(s[h][1][2], s[h][1][3])));
        bool ok = (pm[0] <= m[0] + 11.f) && (pm[1] <= m[1] + 11.f);
        if (!__all(ok)) {
            #pragma unroll
            for (int h = 0; h < 2; ++h) {
                float pr = pm[h];
                pr = fmaxf(pr, __shfl_xor(pr, 16));
                pr = fmaxf(pr, __shfl_xor(pr, 32));
                float mn = fmaxf(m[h], pr);
                float r  = EXP2(m[h] - mn);
                m[h] = mn; llane[h] *= r;
                float r0 = __shfl(r, g * 4 + 0), r1 = __shfl(r, g * 4 + 1);
                float r2 = __shfl(r, g * 4 + 2), r3 = __shfl(r, g * 4 + 3);
                #pragma unroll
                for (int nt = 0; nt < 16; ++nt) {
                    o[0][nt][0] *= (h == 0 ? r0 : 1.f);  // placeholder avoided below
                }
                // correct per-h rescale:
                if (h == 0) {
                    #pragma unroll
                    for (int nt = 0; nt < 16; ++nt) {
                        o[0][nt][0] *= r0; o[0][nt][1] *= r1;
                        o[0][nt][2] *= r2; o[0][nt][3] *= r3;
                    }
                } else {
                    #pragma unroll
                    for (int nt = 0; nt < 16; ++nt) {
                        o[1][nt][0] *= r0; o[1][nt][1] *= r1;
                        o[1][nt][2] *= r2; o[1][nt][3] *= r3;
                    }
                }
            }
        }
        bf16x8 pa0, pa1;
        {
            float p0 = EXP2(s[0][0][0] - m[0]), p1 = EXP2(s[0][0][1] - m[0]);
            float p2 = EXP2(s[0][0][2] - m[0]), p3 = EXP2(s[0][0][3] - m[0]);
            float p4 = EXP2(s[0][1][0] - m[0]), p5 = EXP2(s[0][1][1] - m[0]);
            float p6 = EXP2(s[0][1][2] - m[0]), p7 = EXP2(s[0][1][3] - m[0]);
            llane[0] += ((p0 + p1) + (p2 + p3)) + ((p4 + p5) + (p6 + p7));
            union { int d[4]; bf16x8 v; } u;
            u.d[0] = cvtpk(p0, p1); u.d[1] = cvtpk(p2, p3);
            u.d[2] = cvtpk(p4, p5); u.d[3] = cvtpk(p6, p7);
            pa0 = u.v;
        }
        {
            float p0 = EXP2(s[1][0][0] - m[1]), p1 = EXP2(s[1][0][1] - m[1]);
            float p2 = EXP2(s[1][0][2] - m[1]), p3 = EXP2(s[1][0][3] - m[1]);
            float p4 = EXP2(s[1][1][0] - m[1]), p5 = EXP2(s[1][1][1] - m[1]);
            float p6 = EXP2(s[1][1][2] - m[1]), p7 = EXP2(s[1][1][3] - m[1]);
            llane[1] += ((p0 + p1) + (p2 + p3)) + ((p4 + p5) + (p6 + p7));
            union { int d[4]; bf16x8 v; } u;
            u.d[0] = cvtpk(p0, p1); u.d[1] = cvtpk(p2, p3);
            u.d[2] = cvtpk(p4, p5); u.d[3] = cvtpk(p6, p7);
            pa1 = u.v;
        }

        __builtin_amdgcn_s_setprio(1);
        #pragma unroll
        for (int nt = 0; nt < 16; ++nt) {
            bf16x8 vf = *(const bf16x8*)&Vl[(nt * 16 + c) * 32 + vcol];
            o[0][nt] = __builtin_amdgcn_mfma_f32_16x16x32_bf16(pa0, vf, o[0][nt], 0, 0, 0);
            o[1][nt] = __builtin_amdgcn_mfma_f32_16x16x32_bf16(pa1, vf, o[1][nt], 0, 0, 0);
        }
        __builtin_amdgcn_s_setprio(0);
        buf ^= 1;
    }

    #pragma unroll
    for (int h = 0; h < 2; ++h) {
        float lsum = llane[h];
        lsum += __shfl_xor(lsum, 16);
        lsum += __shfl_xor(lsum, 32);
        float inv = 1.0f / lsum;
        float i0 = __shfl(inv, g * 4 + 0), i1 = __shfl(inv, g * 4 + 1);
        float i2 = __shfl(inv, g * 4 + 2), i3 = __shfl(inv, g * 4 + 3);

        const size_t obase = ((size_t)sidx * BATCH * SEQ + (size_t)b * SEQ + wrow + 16 * h) * DIM;
        for (int nt = 0; nt < 16; ++nt) {
            Opart[obase + (size_t)(g * 4 + 0) * DIM + nt * 16 + c] =
                (unsigned short)f2bf(o[h][nt][0] * i0);
            Opart[obase + (size_t)(g * 4 + 1) * DIM + nt * 16 + c] =
                (unsigned short)f2bf(o[h][nt][1] * i1);
            Opart[obase + (size_t)(g * 4 + 2) * DIM + nt * 16 + c] =
                (unsigned short)f2bf(o[h][nt][2] * i2);
            Opart[obase + (size_t)(g * 4 + 3) * DIM + nt * 16 + c] =
                (unsigned short)f2bf(o[h][nt][3] * i3);
        }
        if (g == 0) {
            ml[(size_t)sidx * BATCH * SEQ + (size_t)b * SEQ + wrow + 16 * h + c] =
                make_float2(m[h], lsum);
        }
    }
}

// ---------------------------------------------------------------------------
// Combine 4 KV-split bf16 partials (log2-domain m): w_s = l_s * 2^(m_s - M)
// ---------------------------------------------------------------------------
__global__ __launch_bounds__(256) void combine_kernel(
    const unsigned short* __restrict__ Opart, const float2* __restrict__ ml,
    float* __restrict__ out)
{
    const int t = threadIdx.x;
    const size_t row = (size_t)blockIdx.x * 4 + (t >> 6);
    const int lane = t & 63;

    float2 e[4];
    float M = -1e30f;
    for (int s = 0; s < 4; ++s) {
        e[s] = ml[(size_t)s * BATCH * SEQ + row];
        M = fmaxf(M, e[s].x);
    }
    float wgt[4], L = 0.f;
    for (int s = 0; s < 4; ++s) { wgt[s] = e[s].y * EXP2(e[s].x - M); L += wgt[s]; }
    float invL = 1.0f / L;

    f32x4 acc = f32x4{0.f, 0.f, 0.f, 0.f};
    for (int s = 0; s < 4; ++s) {
        bf16x4 v = *(const bf16x4*)&Opart[((size_t)s * BATCH * SEQ + row) * DIM + lane * 4];
        float ws = wgt[s] * invL;
        union { unsigned u; float f; } c0, c1, c2, c3;
        c0.u = ((unsigned)(unsigned short)v[0]) << 16;
        c1.u = ((unsigned)(unsigned short)v[1]) << 16;
        c2.u = ((unsigned)(unsigned short)v[2]) << 16;
        c3.u = ((unsigned)(unsigned short)v[3]) << 16;
        acc[0] += ws * c0.f; acc[1] += ws * c1.f;
        acc[2] += ws * c2.f; acc[3] += ws * c3.f;
    }
    *(f32x4*)&out[row * DIM + lane * 4] = acc;
}

__global__ void expand_kernel(const unsigned short* __restrict__ in,
                              float* __restrict__ o) {
    size_t i = (size_t)blockIdx.x * blockDim.x + threadIdx.x;
    union { unsigned u; float f; } v;
    v.u = ((unsigned)in[i]) << 16;
    o[i] = v.f;
}

// ---------------------------------------------------------------------------
extern "C" void kernel_launch(void* const* d_in, const int* in_sizes, int n_in,
                              void* d_out, int out_size, void* d_ws, size_t ws_size,
                              hipStream_t stream) {
    const float* x  = (const float*)d_in[0];
    const float* z  = (const float*)d_in[1];
    const float* Wq = (const float*)d_in[2];
    const float* bq = (const float*)d_in[3];
    const float* Wk = (const float*)d_in[4];
    const float* bk = (const float*)d_in[5];
    const float* Wv = (const float*)d_in[6];
    const float* bv = (const float*)d_in[7];
    float* out = (float*)d_out;

    const size_t TENS = (size_t)BATCH * SEQ * DIM;
    unsigned short* Qb  = (unsigned short*)d_ws;
    unsigned short* Kb  = Qb + TENS;
    unsigned short* Vtb = Kb + TENS;

    const size_t base_bytes = 3 * TENS * sizeof(unsigned short);        // 24 MB
    const size_t need4 = base_bytes + 4 * TENS * sizeof(unsigned short) // 32 MB partials
                       + 4 * (size_t)BATCH * SEQ * sizeof(float2);
    const int nsplit = (ws_size >= need4) ? 4 : 1;

    const float qscale = 0.0625f * LOG2E;  // 1/sqrt(D) * log2(e): base-2 softmax

    proj_kernel<false><<<256, 512, 0, stream>>>(x, Wq, bq, Qb, qscale);
    kv_proj_kernel<<<256, 512, 0, stream>>>(z, Wk, bk, Wv, bv, Kb, Vtb);

    if (nsplit == 4) {
        unsigned short* Op = (unsigned short*)((char*)d_ws + base_bytes);
        float2* mlb = (float2*)((char*)d_ws + base_bytes + 4 * TENS * sizeof(unsigned short));
        fa2_kernel<<<512, 256, 0, stream>>>(Qb, Kb, Vtb, Op, mlb, 4);
        combine_kernel<<<4096, 256, 0, stream>>>(Op, mlb, out);
    } else {
        unsigned short* Op = (unsigned short*)((char*)d_ws + base_bytes);
        float2* mlb = (float2*)((char*)d_ws + base_bytes + TENS * sizeof(unsigned short));
        fa2_kernel<<<128, 256, 0, stream>>>(Qb, Kb, Vtb, Op, mlb, 1);
        expand_kernel<<<TENS / 256, 256, 0, stream>>>(Op, out);
    }
}

// Round 15
// 118.900 us; speedup vs baseline: 1.3399x; 1.0334x over previous
//
#include <hip/hip_runtime.h>
#include <hip/hip_bf16.h>
#include <math.h>

#define BATCH 4
#define SEQ   4096
#define DIM   256
#define AS1 __attribute__((address_space(1)))
#define AS3 __attribute__((address_space(3)))

typedef __attribute__((ext_vector_type(8))) short  bf16x8;
typedef __attribute__((ext_vector_type(4))) short  bf16x4;
typedef __attribute__((ext_vector_type(4))) float  f32x4;
typedef __attribute__((ext_vector_type(4))) int    i32x4;

#define LOG2E 1.44269504088896340736f
#define EXP2(x) __builtin_amdgcn_exp2f(x)   // raw v_exp_f32 (2^x), 1 instr

__device__ __forceinline__ short f2bf(float f) {
    union { float f; unsigned u; } v; v.f = f;
    unsigned r = (v.u + 0x7fffu + ((v.u >> 16) & 1u)) >> 16;
    return (short)r;
}

// pack two f32 -> one dword of 2 bf16 (RTNE), single instruction
__device__ __forceinline__ int cvtpk(float lo, float hi) {
    int r;
    asm("v_cvt_pk_bf16_f32 %0, %1, %2" : "=v"(r) : "v"(lo), "v"(hi));
    return r;
}

__device__ __forceinline__ void gload_lds16(const void* g, void* l) {
    __builtin_amdgcn_global_load_lds((const AS1 void*)g, (AS3 void*)l, 16, 0, 0);
}

// ---------------------------------------------------------------------------
// Fused QKV projection, one launch. Grid 512 x 512thr (8 waves):
//   blocks [0,256):  Q = (x @ Wq^T + bq) * qscale   (row-major bf16)
//   blocks [256,512): K = z @ Wk^T + bk (row-major); Vt = (z @ Wv^T + bv)^T
// Wave w: rows (w&3)*16, output-col half (w>>2).
// ---------------------------------------------------------------------------
__global__ __launch_bounds__(512) void qkv_proj_kernel(
    const float* __restrict__ x, const float* __restrict__ z,
    const float* __restrict__ Wq, const float* __restrict__ bq,
    const float* __restrict__ Wk, const float* __restrict__ bk,
    const float* __restrict__ Wv, const float* __restrict__ bv,
    unsigned short* __restrict__ Qout,   // [16384][256]
    unsigned short* __restrict__ Kout,   // [16384][256]
    unsigned short* __restrict__ Vtout,  // [4][256][4096]
    float qscale)
{
    __shared__ __align__(16) short WldsA[256 * 40];
    __shared__ __align__(16) short WldsB[256 * 40];

    const int t    = threadIdx.x;
    const int wave = t >> 6, lane = t & 63;
    const int rw   = wave & 3, nh = wave >> 2;
    const int c    = lane & 15, g = lane >> 4;

    if (blockIdx.x < 256) {
        // ---------------- Q path ----------------
        const int wrow = blockIdx.x * 64 + rw * 16;
        f32x4 acc[8];
        #pragma unroll
        for (int nt = 0; nt < 8; ++nt) acc[nt] = f32x4{0.f, 0.f, 0.f, 0.f};

        f32x4 wpf[4];
        for (int i = 0; i < 4; ++i) {
            int f = i * 2048 + t * 4;
            wpf[i] = *(const f32x4*)&Wq[(f >> 5) * 256 + (f & 31)];
        }
        f32x4 a0 = *(const f32x4*)&x[(wrow + c) * 256 + g * 8];
        f32x4 a1 = *(const f32x4*)&x[(wrow + c) * 256 + g * 8 + 4];

        for (int ks = 0; ks < 8; ++ks) {
            __syncthreads();
            for (int i = 0; i < 4; ++i) {
                int f = i * 2048 + t * 4;
                bf16x4 s4;
                s4[0] = f2bf(wpf[i][0]); s4[1] = f2bf(wpf[i][1]);
                s4[2] = f2bf(wpf[i][2]); s4[3] = f2bf(wpf[i][3]);
                *(bf16x4*)&WldsA[(f >> 5) * 40 + (f & 31)] = s4;
            }
            __syncthreads();
            bf16x8 af;
            af[0] = f2bf(a0[0]); af[1] = f2bf(a0[1]); af[2] = f2bf(a0[2]); af[3] = f2bf(a0[3]);
            af[4] = f2bf(a1[0]); af[5] = f2bf(a1[1]); af[6] = f2bf(a1[2]); af[7] = f2bf(a1[3]);
            if (ks < 7) {
                for (int i = 0; i < 4; ++i) {
                    int f = i * 2048 + t * 4;
                    wpf[i] = *(const f32x4*)&Wq[(f >> 5) * 256 + (ks + 1) * 32 + (f & 31)];
                }
                a0 = *(const f32x4*)&x[(wrow + c) * 256 + (ks + 1) * 32 + g * 8];
                a1 = *(const f32x4*)&x[(wrow + c) * 256 + (ks + 1) * 32 + g * 8 + 4];
            }
            __builtin_amdgcn_s_setprio(1);
            #pragma unroll
            for (int nt = 0; nt < 8; ++nt) {
                int e = (nh * 8 + nt) * 16 + c;
                bf16x8 bfr = *(const bf16x8*)&WldsA[e * 40 + g * 8];
                acc[nt] = __builtin_amdgcn_mfma_f32_16x16x32_bf16(af, bfr, acc[nt], 0, 0, 0);
            }
            __builtin_amdgcn_s_setprio(0);
        }
        for (int nt = 0; nt < 8; ++nt) {
            int e = (nh * 8 + nt) * 16 + c;
            float bv_ = bq[e];
            for (int j = 0; j < 4; ++j)
                Qout[(size_t)(wrow + g * 4 + j) * 256 + e] =
                    (unsigned short)f2bf((acc[nt][j] + bv_) * qscale);
        }
    } else {
        // ---------------- K+V path ----------------
        const int wrow = (blockIdx.x - 256) * 64 + rw * 16;
        f32x4 acck[8], accv[8];
        #pragma unroll
        for (int nt = 0; nt < 8; ++nt) {
            acck[nt] = f32x4{0.f, 0.f, 0.f, 0.f};
            accv[nt] = f32x4{0.f, 0.f, 0.f, 0.f};
        }

        f32x4 wpfk[4], wpfv[4];
        for (int i = 0; i < 4; ++i) {
            int f = i * 2048 + t * 4;
            wpfk[i] = *(const f32x4*)&Wk[(f >> 5) * 256 + (f & 31)];
            wpfv[i] = *(const f32x4*)&Wv[(f >> 5) * 256 + (f & 31)];
        }
        f32x4 a0 = *(const f32x4*)&z[(wrow + c) * 256 + g * 8];
        f32x4 a1 = *(const f32x4*)&z[(wrow + c) * 256 + g * 8 + 4];

        for (int ks = 0; ks < 8; ++ks) {
            __syncthreads();
            for (int i = 0; i < 4; ++i) {
                int f = i * 2048 + t * 4;
                bf16x4 sk, sv;
                sk[0] = f2bf(wpfk[i][0]); sk[1] = f2bf(wpfk[i][1]);
                sk[2] = f2bf(wpfk[i][2]); sk[3] = f2bf(wpfk[i][3]);
                sv[0] = f2bf(wpfv[i][0]); sv[1] = f2bf(wpfv[i][1]);
                sv[2] = f2bf(wpfv[i][2]); sv[3] = f2bf(wpfv[i][3]);
                *(bf16x4*)&WldsA[(f >> 5) * 40 + (f & 31)] = sk;
                *(bf16x4*)&WldsB[(f >> 5) * 40 + (f & 31)] = sv;
            }
            __syncthreads();
            bf16x8 af;
            af[0] = f2bf(a0[0]); af[1] = f2bf(a0[1]); af[2] = f2bf(a0[2]); af[3] = f2bf(a0[3]);
            af[4] = f2bf(a1[0]); af[5] = f2bf(a1[1]); af[6] = f2bf(a1[2]); af[7] = f2bf(a1[3]);
            if (ks < 7) {
                for (int i = 0; i < 4; ++i) {
                    int f = i * 2048 + t * 4;
                    wpfk[i] = *(const f32x4*)&Wk[(f >> 5) * 256 + (ks + 1) * 32 + (f & 31)];
                    wpfv[i] = *(const f32x4*)&Wv[(f >> 5) * 256 + (ks + 1) * 32 + (f & 31)];
                }
                a0 = *(const f32x4*)&z[(wrow + c) * 256 + (ks + 1) * 32 + g * 8];
                a1 = *(const f32x4*)&z[(wrow + c) * 256 + (ks + 1) * 32 + g * 8 + 4];
            }
            __builtin_amdgcn_s_setprio(1);
            #pragma unroll
            for (int nt = 0; nt < 8; ++nt) {
                int e = (nh * 8 + nt) * 16 + c;
                bf16x8 bk_ = *(const bf16x8*)&WldsA[e * 40 + g * 8];
                acck[nt] = __builtin_amdgcn_mfma_f32_16x16x32_bf16(af, bk_, acck[nt], 0, 0, 0);
                bf16x8 bv_ = *(const bf16x8*)&WldsB[e * 40 + g * 8];
                accv[nt] = __builtin_amdgcn_mfma_f32_16x16x32_bf16(af, bv_, accv[nt], 0, 0, 0);
            }
            __builtin_amdgcn_s_setprio(0);
        }

        for (int nt = 0; nt < 8; ++nt) {
            int e = (nh * 8 + nt) * 16 + c;
            float bb = bk[e];
            for (int j = 0; j < 4; ++j)
                Kout[(size_t)(wrow + g * 4 + j) * 256 + e] =
                    (unsigned short)f2bf(acck[nt][j] + bb);
        }
        const int nb = wrow >> 12, n0 = wrow & 4095;
        for (int nt = 0; nt < 8; ++nt) {
            int e = (nh * 8 + nt) * 16 + c;
            float bb = bv[e];
            bf16x4 s4;
            s4[0] = f2bf(accv[nt][0] + bb); s4[1] = f2bf(accv[nt][1] + bb);
            s4[2] = f2bf(accv[nt][2] + bb); s4[3] = f2bf(accv[nt][3] + bb);
            *(bf16x4*)&Vtout[((size_t)nb * DIM + e) * SEQ + n0 + g * 4] = s4;
        }
    }
}

// ---------------------------------------------------------------------------
// Flash attention: single barrier/tile, bf16 partials.
// 4 waves x 32 q-rows, KVB=32, dbuf, base-2 softmax (raw v_exp), cvt_pk P.
// ---------------------------------------------------------------------------
#define KVB 32

__global__ __launch_bounds__(256, 2) void fa2_kernel(
    const unsigned short* __restrict__ Q,   // bf16, pre-scaled (log2 domain)
    const unsigned short* __restrict__ K,
    const unsigned short* __restrict__ Vt,
    unsigned short* __restrict__ Opart,     // [nsplit][4][4096][256] bf16 (l-normalized)
    float2* __restrict__ ml,                // [nsplit][4*4096]  (m in log2 domain)
    int nsplit)
{
    __shared__ __align__(16) unsigned short Klds[2][KVB * 256];
    __shared__ __align__(16) unsigned short Vlds[2][256 * KVB];

    const int t = threadIdx.x;
    const int w = t >> 6, lane = t & 63;
    const int c = lane & 15, g = lane >> 4;

    int b, sidx, qt;
    if (nsplit == 4) {
        int xcd  = blockIdx.x & 7;
        int rest = blockIdx.x >> 3;
        int combo = (xcd << 1) | (rest >> 5);
        qt   = rest & 31;
        b    = combo >> 2;
        sidx = combo & 3;
    } else {
        qt   = blockIdx.x & 31;
        b    = blockIdx.x >> 5;
        sidx = 0;
    }
    const int ts = (sidx * 128) / nsplit;
    const int te = ((sidx + 1) * 128) / nsplit;

    const int wrow = qt * 128 + w * 32;

    bf16x8 qf[2][8];
    #pragma unroll
    for (int h = 0; h < 2; ++h) {
        const unsigned short* Qrow = &Q[((size_t)b * SEQ + wrow + 16 * h + c) * DIM];
        #pragma unroll
        for (int ks = 0; ks < 8; ++ks)
            qf[h][ks] = *(const bf16x8*)&Qrow[ks * 32 + g * 8];
    }

    f32x4 o[2][16];
    #pragma unroll
    for (int h = 0; h < 2; ++h)
        #pragma unroll
        for (int nt = 0; nt < 16; ++nt) o[h][nt] = f32x4{0.f, 0.f, 0.f, 0.f};
    float m[2]     = {-1e30f, -1e30f};
    float llane[2] = {0.f, 0.f};

    const char* Kb_ = (const char*)&K[(size_t)b * SEQ * DIM];
    const char* Vb_ = (const char*)&Vt[(size_t)b * DIM * SEQ];

    const int l31 = lane & 31;
    int koff[4], voff[4], dstb[4];
    const int vsw = ((lane >> 2) & 3) ^ ((lane >> 4) & 3);
    const int vcb = ((lane & 3) ^ vsw) << 4;
    #pragma unroll
    for (int ii = 0; ii < 4; ++ii) {
        int kr = 8 * w + 2 * ii + (lane >> 5);
        int sc = (kr & 3) | ((kr & 8) >> 1);              // sigma_c
        koff[ii] = kr * 512 + ((l31 ^ sc) << 4);
        int vr = 64 * w + 16 * ii + (lane >> 2);
        voff[ii] = vr * (SEQ * 2) + vcb;
        dstb[ii] = (4 * w + ii) * 1024;
    }

    #define STAGE(kt_, buf_) do {                                              \
        const size_t kb_ = (size_t)(kt_) * (KVB * DIM * 2);                    \
        const size_t vb_ = (size_t)(kt_) * (KVB * 2);                          \
        _Pragma("unroll")                                                      \
        for (int ii = 0; ii < 4; ++ii) {                                       \
            gload_lds16(Kb_ + kb_ + koff[ii], (char*)&Klds[buf_][0] + dstb[ii]); \
            gload_lds16(Vb_ + vb_ + voff[ii], (char*)&Vlds[buf_][0] + dstb[ii]); \
        }                                                                      \
    } while (0)

    STAGE(ts, 0);
    int buf = 0;

    const int xk   = (c & 7) << 3;
    const int rphi = ((c & 3) + 8 * (c >> 2));
    const int vcol = (g * 8) ^ ((((c & 3) ^ ((c >> 2) & 3))) << 3);

    for (int kt = ts; kt < te; ++kt) {
        // Single barrier per tile: own vmcnt(0) proves this wave's tile-kt
        // DMAs landed; barrier then jointly proves (a) ALL waves' kt DMAs
        // landed, (b) all waves finished reading buf^1.
        asm volatile("s_waitcnt vmcnt(0)" ::: "memory");
        __builtin_amdgcn_s_barrier();
        if (kt + 1 < te) STAGE(kt + 1, buf ^ 1);

        const unsigned short* Kl = &Klds[buf][0];
        const unsigned short* Vl = &Vlds[buf][0];

        f32x4 s[2][2];
        #pragma unroll
        for (int h = 0; h < 2; ++h) {
            s[h][0] = f32x4{0.f, 0.f, 0.f, 0.f};
            s[h][1] = f32x4{0.f, 0.f, 0.f, 0.f};
        }
        __builtin_amdgcn_s_setprio(1);
        #pragma unroll
        for (int ks = 0; ks < 8; ++ks) {
            int off = (ks * 32 + g * 8) ^ xk;
            bf16x8 kf0 = *(const bf16x8*)&Kl[rphi * 256 + off];
            bf16x8 kf1 = *(const bf16x8*)&Kl[(rphi + 4) * 256 + off];
            s[0][0] = __builtin_amdgcn_mfma_f32_16x16x32_bf16(kf0, qf[0][ks], s[0][0], 0, 0, 0);
            s[1][0] = __builtin_amdgcn_mfma_f32_16x16x32_bf16(kf0, qf[1][ks], s[1][0], 0, 0, 0);
            s[0][1] = __builtin_amdgcn_mfma_f32_16x16x32_bf16(kf1, qf[0][ks], s[0][1], 0, 0, 0);
            s[1][1] = __builtin_amdgcn_mfma_f32_16x16x32_bf16(kf1, qf[1][ks], s[1][1], 0, 0, 0);
        }
        __builtin_amdgcn_s_setprio(0);

        // defer-max softmax in log2 domain (threshold 11 bits ~ 8 nats)
        float pm[2];
        #pragma unroll
        for (int h = 0; h < 2; ++h)
            pm[h] = fmaxf(fmaxf(fmaxf(s[h][0][0], s[h][0][1]), fmaxf(s[h][0][2], s[h][0][3])),
                          fmaxf(fmaxf(s[h][1][0], s[h][1][1]), fmaxf(s[h][1][2], s[h][1][3])));
        bool ok = (pm[0] <= m[0] + 11.f) && (pm[1] <= m[1] + 11.f);
        if (!__all(ok)) {
            #pragma unroll
            for (int h = 0; h < 2; ++h) {
                float pr = pm[h];
                pr = fmaxf(pr, __shfl_xor(pr, 16));
                pr = fmaxf(pr, __shfl_xor(pr, 32));
                float mn = fmaxf(m[h], pr);
                float r  = EXP2(m[h] - mn);
                m[h] = mn; llane[h] *= r;
                float r0 = __shfl(r, g * 4 + 0), r1 = __shfl(r, g * 4 + 1);
                float r2 = __shfl(r, g * 4 + 2), r3 = __shfl(r, g * 4 + 3);
                if (h == 0) {
                    #pragma unroll
                    for (int nt = 0; nt < 16; ++nt) {
                        o[0][nt][0] *= r0; o[0][nt][1] *= r1;
                        o[0][nt][2] *= r2; o[0][nt][3] *= r3;
                    }
                } else {
                    #pragma unroll
                    for (int nt = 0; nt < 16; ++nt) {
                        o[1][nt][0] *= r0; o[1][nt][1] *= r1;
                        o[1][nt][2] *= r2; o[1][nt][3] *= r3;
                    }
                }
            }
        }
        bf16x8 pa0, pa1;
        {
            float p0 = EXP2(s[0][0][0] - m[0]), p1 = EXP2(s[0][0][1] - m[0]);
            float p2 = EXP2(s[0][0][2] - m[0]), p3 = EXP2(s[0][0][3] - m[0]);
            float p4 = EXP2(s[0][1][0] - m[0]), p5 = EXP2(s[0][1][1] - m[0]);
            float p6 = EXP2(s[0][1][2] - m[0]), p7 = EXP2(s[0][1][3] - m[0]);
            llane[0] += ((p0 + p1) + (p2 + p3)) + ((p4 + p5) + (p6 + p7));
            union { int d[4]; bf16x8 v; } u;
            u.d[0] = cvtpk(p0, p1); u.d[1] = cvtpk(p2, p3);
            u.d[2] = cvtpk(p4, p5); u.d[3] = cvtpk(p6, p7);
            pa0 = u.v;
        }
        {
            float p0 = EXP2(s[1][0][0] - m[1]), p1 = EXP2(s[1][0][1] - m[1]);
            float p2 = EXP2(s[1][0][2] - m[1]), p3 = EXP2(s[1][0][3] - m[1]);
            float p4 = EXP2(s[1][1][0] - m[1]), p5 = EXP2(s[1][1][1] - m[1]);
            float p6 = EXP2(s[1][1][2] - m[1]), p7 = EXP2(s[1][1][3] - m[1]);
            llane[1] += ((p0 + p1) + (p2 + p3)) + ((p4 + p5) + (p6 + p7));
            union { int d[4]; bf16x8 v; } u;
            u.d[0] = cvtpk(p0, p1); u.d[1] = cvtpk(p2, p3);
            u.d[2] = cvtpk(p4, p5); u.d[3] = cvtpk(p6, p7);
            pa1 = u.v;
        }

        __builtin_amdgcn_s_setprio(1);
        #pragma unroll
        for (int nt = 0; nt < 16; ++nt) {
            bf16x8 vf = *(const bf16x8*)&Vl[(nt * 16 + c) * 32 + vcol];
            o[0][nt] = __builtin_amdgcn_mfma_f32_16x16x32_bf16(pa0, vf, o[0][nt], 0, 0, 0);
            o[1][nt] = __builtin_amdgcn_mfma_f32_16x16x32_bf16(pa1, vf, o[1][nt], 0, 0, 0);
        }
        __builtin_amdgcn_s_setprio(0);
        buf ^= 1;
    }

    #pragma unroll
    for (int h = 0; h < 2; ++h) {
        float lsum = llane[h];
        lsum += __shfl_xor(lsum, 16);
        lsum += __shfl_xor(lsum, 32);
        float inv = 1.0f / lsum;
        float i0 = __shfl(inv, g * 4 + 0), i1 = __shfl(inv, g * 4 + 1);
        float i2 = __shfl(inv, g * 4 + 2), i3 = __shfl(inv, g * 4 + 3);

        const size_t obase = ((size_t)sidx * BATCH * SEQ + (size_t)b * SEQ + wrow + 16 * h) * DIM;
        for (int nt = 0; nt < 16; ++nt) {
            Opart[obase + (size_t)(g * 4 + 0) * DIM + nt * 16 + c] =
                (unsigned short)f2bf(o[h][nt][0] * i0);
            Opart[obase + (size_t)(g * 4 + 1) * DIM + nt * 16 + c] =
                (unsigned short)f2bf(o[h][nt][1] * i1);
            Opart[obase + (size_t)(g * 4 + 2) * DIM + nt * 16 + c] =
                (unsigned short)f2bf(o[h][nt][2] * i2);
            Opart[obase + (size_t)(g * 4 + 3) * DIM + nt * 16 + c] =
                (unsigned short)f2bf(o[h][nt][3] * i3);
        }
        if (g == 0) {
            ml[(size_t)sidx * BATCH * SEQ + (size_t)b * SEQ + wrow + 16 * h + c] =
                make_float2(m[h], lsum);
        }
    }
}

// ---------------------------------------------------------------------------
// Combine 4 KV-split bf16 partials (log2-domain m): w_s = l_s * 2^(m_s - M)
// 32 lanes/row x 8 elements: 16B loads, 2x16B stores per lane.
// ---------------------------------------------------------------------------
__global__ __launch_bounds__(256) void combine_kernel(
    const unsigned short* __restrict__ Opart, const float2* __restrict__ ml,
    float* __restrict__ out)
{
    const int t = threadIdx.x;
    const size_t row = (size_t)blockIdx.x * 8 + (t >> 5);  // 2048 blocks
    const int lane = t & 31;

    float2 e[4];
    float M = -1e30f;
    #pragma unroll
    for (int s = 0; s < 4; ++s) {
        e[s] = ml[(size_t)s * BATCH * SEQ + row];
        M = fmaxf(M, e[s].x);
    }
    float wgt[4], L = 0.f;
    #pragma unroll
    for (int s = 0; s < 4; ++s) { wgt[s] = e[s].y * EXP2(e[s].x - M); L += wgt[s]; }
    float invL = 1.0f / L;

    float acc[8] = {0.f, 0.f, 0.f, 0.f, 0.f, 0.f, 0.f, 0.f};
    #pragma unroll
    for (int s = 0; s < 4; ++s) {
        bf16x8 v = *(const bf16x8*)&Opart[((size_t)s * BATCH * SEQ + row) * DIM + lane * 8];
        float ws = wgt[s] * invL;
        #pragma unroll
        for (int j = 0; j < 8; ++j) {
            union { unsigned u; float f; } cv;
            cv.u = ((unsigned)(unsigned short)v[j]) << 16;
            acc[j] += ws * cv.f;
        }
    }
    f32x4 o0, o1;
    o0[0] = acc[0]; o0[1] = acc[1]; o0[2] = acc[2]; o0[3] = acc[3];
    o1[0] = acc[4]; o1[1] = acc[5]; o1[2] = acc[6]; o1[3] = acc[7];
    *(f32x4*)&out[row * DIM + lane * 8]     = o0;
    *(f32x4*)&out[row * DIM + lane * 8 + 4] = o1;
}

__global__ void expand_kernel(const unsigned short* __restrict__ in,
                              float* __restrict__ o) {
    size_t i = (size_t)blockIdx.x * blockDim.x + threadIdx.x;
    union { unsigned u; float f; } v;
    v.u = ((unsigned)in[i]) << 16;
    o[i] = v.f;
}

// ---------------------------------------------------------------------------
extern "C" void kernel_launch(void* const* d_in, const int* in_sizes, int n_in,
                              void* d_out, int out_size, void* d_ws, size_t ws_size,
                              hipStream_t stream) {
    const float* x  = (const float*)d_in[0];
    const float* z  = (const float*)d_in[1];
    const float* Wq = (const float*)d_in[2];
    const float* bq = (const float*)d_in[3];
    const float* Wk = (const float*)d_in[4];
    const float* bk = (const float*)d_in[5];
    const float* Wv = (const float*)d_in[6];
    const float* bv = (const float*)d_in[7];
    float* out = (float*)d_out;

    const size_t TENS = (size_t)BATCH * SEQ * DIM;
    unsigned short* Qb  = (unsigned short*)d_ws;
    unsigned short* Kb  = Qb + TENS;
    unsigned short* Vtb = Kb + TENS;

    const size_t base_bytes = 3 * TENS * sizeof(unsigned short);        // 24 MB
    const size_t need4 = base_bytes + 4 * TENS * sizeof(unsigned short) // 32 MB partials
                       + 4 * (size_t)BATCH * SEQ * sizeof(float2);
    const int nsplit = (ws_size >= need4) ? 4 : 1;

    const float qscale = 0.0625f * LOG2E;  // 1/sqrt(D) * log2(e): base-2 softmax

    qkv_proj_kernel<<<512, 512, 0, stream>>>(x, z, Wq, bq, Wk, bk, Wv, bv,
                                             Qb, Kb, Vtb, qscale);

    if (nsplit == 4) {
        unsigned short* Op = (unsigned short*)((char*)d_ws + base_bytes);
        float2* mlb = (float2*)((char*)d_ws + base_bytes + 4 * TENS * sizeof(unsigned short));
        fa2_kernel<<<512, 256, 0, stream>>>(Qb, Kb, Vtb, Op, mlb, 4);
        combine_kernel<<<2048, 256, 0, stream>>>(Op, mlb, out);
    } else {
        unsigned short* Op = (unsigned short*)((char*)d_ws + base_bytes);
        float2* mlb = (float2*)((char*)d_ws + base_bytes + TENS * sizeof(unsigned short));
        fa2_kernel<<<128, 256, 0, stream>>>(Qb, Kb, Vtb, Op, mlb, 1);
        expand_kernel<<<TENS / 256, 256, 0, stream>>>(Op, out);
    }
}